// Round 5
// baseline (310.671 us; speedup 1.0000x reference)
//
#include <hip/hip_runtime.h>

// MultiHeadAttention: B=4, S=2048, D=1024, H=16, dk=dv=64.
// Inputs fp32, output fp32; compute bf16 MFMA.
// R9: attention computes S^T = K·Q^T so P^T exits MFMA in a layout reachable
// from the PV B-operand by a pure lane permutation -- no P LDS round-trip.
// R10: attn VALU diet: builtin exp2, ones-MFMA denominator, v_perm pack.
// R11: 64 q-rows/wave. NEUTRAL -> ds_read BW was not binding.
// R12: ds_bpermute -> permlane32/16_swap: conflicts 8.4M->0, attn 112->83us.
// R13: gemm_bt double-buffered, 1 barrier/K-step (-9us).
// R14: GEMM epilogues were scalar stores (QK: 64 ushort/thread, out: dword).
// Swap MFMA operands (free in-register transpose of D): thread then holds
// row=lr with 4 consecutive cols q4*4+p -> float4/ushortx4 stores, 4 q4-lanes
// complete contiguous 64B/32B row runs. V region keeps unswapped order (VT
// is [d][s], vectorized along s) -> QKV split into QK (swapped) + V launches.

typedef __attribute__((ext_vector_type(8))) short bf16x8;   // 8 bf16 = 4 VGPRs
typedef __attribute__((ext_vector_type(4))) float f32x4;
typedef __attribute__((ext_vector_type(4))) unsigned short ushortx4;
typedef __attribute__((ext_vector_type(2))) unsigned int uint2v;

__device__ __forceinline__ unsigned short f2bf(float x) {   // RNE
    unsigned int u = __float_as_uint(x);
    u += 0x7FFFu + ((u >> 16) & 1u);
    return (unsigned short)(u >> 16);
}
// pack two floats as truncated bf16 pair: [hi.bf16 : lo.bf16] -- v_perm_b32
__device__ __forceinline__ unsigned int pack_bf2(float hi, float lo) {
    return __builtin_amdgcn_perm(__float_as_uint(hi), __float_as_uint(lo), 0x07060302u);
}

// async 16B global -> LDS (lds dest wave-uniform; HW adds lane*16)
__device__ __forceinline__ void gload_lds16(const unsigned short* g, unsigned short* lds) {
    __builtin_amdgcn_global_load_lds(
        (const __attribute__((address_space(1))) unsigned int*)g,
        (__attribute__((address_space(3))) unsigned int*)lds,
        16, 0, 0);
}

// ---------------------------------------------------------------------------
// One merged pack kernel. Sections by blockIdx.x:
//  [0,4096):      XB  = bf16(x)
//  [4096,5632):   WQKVT[n][d] (Wq pre-scaled by 0.125*log2e)
//  [5632,6144):   WOT[n][k] = Wo[k][n]
__global__ __launch_bounds__(256) void pack_all(
    const float* __restrict__ x,
    const float* __restrict__ Wq,
    const float* __restrict__ Wk,
    const float* __restrict__ Wv,
    const float* __restrict__ Wo,
    unsigned short* __restrict__ XB,
    unsigned short* __restrict__ WQKVT,
    unsigned short* __restrict__ WOT)
{
    const int bid = blockIdx.x;
    bf16x8 v;
    if (bid < 4096) {
        size_t base = ((size_t)bid * 256 + threadIdx.x) * 8;
        float4 f0 = *(const float4*)&x[base];
        float4 f1 = *(const float4*)&x[base + 4];
        v[0] = f2bf(f0.x); v[1] = f2bf(f0.y); v[2] = f2bf(f0.z); v[3] = f2bf(f0.w);
        v[4] = f2bf(f1.x); v[5] = f2bf(f1.y); v[6] = f2bf(f1.z); v[7] = f2bf(f1.w);
        *(bf16x8*)&XB[base] = v;
    } else if (bid < 5632) {
        int i = (bid - 4096) * 256 + threadIdx.x;
        int d0 = (i * 8) & 1023;
        int n  = (i * 8) >> 10;
        int part = n >> 10;
        int hkk  = n & 1023;
        int h = hkk >> 6, kk = hkk & 63;
        const float* W = (part == 0) ? Wq : ((part == 1) ? Wk : Wv);
        float scale = (part == 0) ? 0.125f * 1.44269504088896f : 1.0f;
        #pragma unroll
        for (int e = 0; e < 8; ++e)
            v[e] = f2bf(W[(h << 16) + ((d0 + e) << 6) + kk] * scale);
        *(bf16x8*)&WQKVT[(size_t)n * 1024 + d0] = v;
    } else {
        int i = (bid - 5632) * 256 + threadIdx.x;
        int k0 = (i * 8) & 1023;
        int n  = (i * 8) >> 10;
        #pragma unroll
        for (int e = 0; e < 8; ++e)
            v[e] = f2bf(Wo[(size_t)(k0 + e) * 1024 + n]);
        *(bf16x8*)&WOT[(size_t)n * 1024 + k0] = v;
    }
}

// ---------------------------------------------------------------------------
// C = A[M][K] @ Bt[N][K]^T, A/Bt bf16 row-major, global_load_lds staging into
// double-buffered LDS, 1 barrier per K-step (DMA t+1 in flight across compute t).
// CMODE 0: fp32 C, swapped operands -> float4 row stores.
// CMODE 1: bf16 C (QK), swapped operands -> ushortx4 row stores.
// CMODE 2: VT transposed output, unswapped (vectorized along s=M).
// BN=128: 4 waves 2x2, 4x4 frags.  BN=64: 4 waves 4x1, 2x4 frags.
template<int CMODE, int BN>
__global__ __launch_bounds__(256) void gemm_bt(
    const unsigned short* __restrict__ A,
    const unsigned short* __restrict__ Bt,
    void* __restrict__ Cv,
    unsigned short* __restrict__ VT,
    int M, int N, int K, int ldc)
{
    __shared__ __align__(16) unsigned short As[2][128 * 32];
    __shared__ __align__(16) unsigned short Bs[2][BN * 32];
    const int m0 = blockIdx.y * 128;
    const int n0 = blockIdx.x * BN;
    const int tid  = threadIdx.x;
    const int w    = tid >> 6, lane = tid & 63;
    const int q4   = lane >> 4, lr  = lane & 15;
    constexpr int MI = (BN == 128) ? 4 : 2;
    constexpr bool SWAP = (CMODE != 2);   // D transposed in-register
    const int rowBase = (BN == 128) ? (w >> 1) * 64 : w * 32;
    const int colBase = (BN == 128) ? (w & 1) * 64 : 0;

    const int ch   = tid & 3;
    const int row0 = tid >> 2;
    const int ldsOff = w * 512;   // halfwords; HW adds lane*16B

    const unsigned short* aP0 = &A [(size_t)(m0 + row0)      * K + ch * 8];
    const unsigned short* aP1 = &A [(size_t)(m0 + row0 + 64) * K + ch * 8];
    const unsigned short* bP0 = &Bt[(size_t)(n0 + row0)      * K + ch * 8];
    const unsigned short* bP1 = (BN == 128)
        ? &Bt[(size_t)(n0 + row0 + 64) * K + ch * 8] : nullptr;

    auto dma = [&](int buf, int k0) {
        gload_lds16(aP0 + k0, &As[buf][ldsOff]);
        gload_lds16(aP1 + k0, &As[buf][2048 + ldsOff]);
        gload_lds16(bP0 + k0, &Bs[buf][ldsOff]);
        if (BN == 128)
            gload_lds16(bP1 + k0, &Bs[buf][2048 + ldsOff]);
    };

    f32x4 acc[MI][4] = {};
    dma(0, 0);
    int cur = 0;

    for (int k0 = 0; k0 < K; k0 += 32) {
        __syncthreads();                          // drains DMA(k0) -> buf[cur] ready
        if (k0 + 32 < K) dma(cur ^ 1, k0 + 32);   // in flight during compute

        bf16x8 af[MI], bfv[4];
        #pragma unroll
        for (int i = 0; i < MI; ++i)
            af[i] = *(const bf16x8*)&As[cur][(rowBase + i * 16 + lr) * 32 + q4 * 8];
        #pragma unroll
        for (int j = 0; j < 4; ++j)
            bfv[j] = *(const bf16x8*)&Bs[cur][(colBase + j * 16 + lr) * 32 + q4 * 8];
        #pragma unroll
        for (int i = 0; i < MI; ++i)
            #pragma unroll
            for (int j = 0; j < 4; ++j) {
                if (SWAP)
                    acc[i][j] = __builtin_amdgcn_mfma_f32_16x16x32_bf16(bfv[j], af[i], acc[i][j], 0, 0, 0);
                else
                    acc[i][j] = __builtin_amdgcn_mfma_f32_16x16x32_bf16(af[i], bfv[j], acc[i][j], 0, 0, 0);
            }
        cur ^= 1;
    }

    #pragma unroll
    for (int i = 0; i < MI; ++i) {
        #pragma unroll
        for (int j = 0; j < 4; ++j) {
            if constexpr (CMODE == 0) {
                // swapped: row = ..+lr, cols = ..+q4*4+p  -> float4 store
                const int row = m0 + rowBase + i * 16 + lr;
                const int col = n0 + colBase + j * 16 + q4 * 4;
                float* C = (float*)Cv;
                float4 fv = { acc[i][j][0], acc[i][j][1], acc[i][j][2], acc[i][j][3] };
                *(float4*)&C[(size_t)row * ldc + col] = fv;
            } else if constexpr (CMODE == 1) {
                const int row = m0 + rowBase + i * 16 + lr;
                const int col = n0 + colBase + j * 16 + q4 * 4;
                unsigned short* C = (unsigned short*)Cv;
                ushortx4 v;
                #pragma unroll
                for (int p = 0; p < 4; ++p) v[p] = f2bf(acc[i][j][p]);
                *(ushortx4*)&C[(size_t)row * 2048 + col] = v;
            } else {
                // unswapped: row = ..+q4*4+p (s-dim), col = ..+lr (head*64+d)
                const int row = m0 + rowBase + i * 16 + q4 * 4;
                const int col = n0 + colBase + j * 16 + lr;
                const int hh = col >> 6, dd = col & 63;
                const int bb = row >> 11, ss = row & 2047;
                ushortx4 v;
                #pragma unroll
                for (int p = 0; p < 4; ++p) v[p] = f2bf(acc[i][j][p]);
                *(ushortx4*)&VT[((size_t)(bb * 16 + hh) * 64 + dd) * 2048 + ss] = v;
            }
        }
    }
}

// ---------------------------------------------------------------------------
// Flash attention, transposed-P scheme.  QK[8192][2048] bf16 (Q|K),
// VT[(b*16+h)*64+d][2048] bf16.  WG = (bh, 256-q block); wave w: 64 q as
// 4 subtiles u.  64-key tiles, K/V in XOR-swizzled stride-64 double buffers
// filled by global_load_lds; S^T = K·Q^T; P^T moved to PV B-frags via
// permlane32_swap + permlane16_swap (pure VALU, no LDS); O^T = V^T·P^T.
// Softmax denominator accumulated by a ones-A-frag MFMA.
__global__ __launch_bounds__(256, 2) void attn_flash(
    const unsigned short* __restrict__ QK,
    const unsigned short* __restrict__ VT,
    unsigned short* __restrict__ HC)        // [8192][1024] bf16
{
    const int bh  = blockIdx.x;   // b*16+h  (fastest dim -> XCD-pinned K/V reuse)
    const int qb  = blockIdx.y;   // 0..7
    const int b   = bh >> 4, h = bh & 15;
    const int tid = threadIdx.x;
    const int w   = tid >> 6, lane = tid & 63;
    const int q4  = lane >> 4, lr  = lane & 15;

    __shared__ __align__(16) unsigned short Ks [2][64 * 64];   // [key][dk] swizzled
    __shared__ __align__(16) unsigned short Vts[2][64 * 64];   // [d][key]  swizzled

    // DMA mapping: round R covers rows R*32+(tid>>3), chunk slot tid&7.
    const int drow   = tid >> 3;                       // 0..31
    const int gchunk = (tid & 7) ^ (drow & 7);         // global chunk for slot tid&7
    const unsigned short* Kg = QK + (size_t)(b * 2048) * 2048 + 1024 + h * 64;
    const unsigned short* Vg = VT + (size_t)bh * 64 * 2048;
    // running global pointers (advance per 64-key tile)
    const unsigned short* kP0 = Kg + (size_t)(drow)      * 2048 + gchunk * 8;
    const unsigned short* kP1 = Kg + (size_t)(drow + 32) * 2048 + gchunk * 8;
    const unsigned short* vP0 = Vg + (size_t)(drow)      * 2048 + gchunk * 8;
    const unsigned short* vP1 = Vg + (size_t)(drow + 32) * 2048 + gchunk * 8;
    const int ldsOff = w * 512;                        // halfwords; +lane*8 by HW

    auto dma = [&](int buf, int t) {
        gload_lds16(kP0 + (size_t)t * 131072, &Ks [buf][ldsOff]);
        gload_lds16(kP1 + (size_t)t * 131072, &Ks [buf][2048 + ldsOff]);
        gload_lds16(vP0 + t * 64,             &Vts[buf][ldsOff]);
        gload_lds16(vP1 + t * 64,             &Vts[buf][2048 + ldsOff]);
    };

    dma(0, 0);

    const int qrow0 = b * 2048 + qb * 256 + w * 64;
    bf16x8 qf[4][2];   // B-frag of Q^T == A-frag of Q: Q[q=lr][dk=c*32+q4*8+j]
    #pragma unroll
    for (int u = 0; u < 4; ++u)
        #pragma unroll
        for (int c = 0; c < 2; ++c)
            qf[u][c] = *(const bf16x8*)&QK[(size_t)(qrow0 + u * 16 + lr) * 2048
                                           + h * 64 + c * 32 + q4 * 8];

    const int lr7 = lr & 7;

    // ones A-fragment (bf16 1.0) for denominator row-sum MFMA
    const short oneb = (short)0x3F80;
    const bf16x8 onesf = { oneb, oneb, oneb, oneb, oneb, oneb, oneb, oneb };

    f32x4 o[4][4] = {};      // O^T[d=jd*16+q4*4+p][q=u*16+lr]
    f32x4 lsum[4] = {};      // denominator: all rows equal = sum_k P^T[k][q=lr]
    int cur = 0;

    for (int t = 0; t < 32; ++t) {
        __syncthreads();                       // drains DMA(t) -> buf[cur] ready
        if (t + 1 < 32) dma(cur ^ 1, t + 1);   // in flight during compute

        #pragma unroll
        for (int kc = 0; kc < 2; ++kc) {
            // --- S^T for this 32-key chunk (2 mt subtiles) ---
            unsigned int pk[4][2][2];          // packed P^T words [u][ml][i]
            #pragma unroll
            for (int ml = 0; ml < 2; ++ml) {
                const int mt = kc * 2 + ml;
                f32x4 st[4] = {};
                #pragma unroll
                for (int c = 0; c < 2; ++c) {
                    const int slot = (c * 4 + q4) ^ lr7;
                    bf16x8 kf = *(const bf16x8*)&Ks[cur][(mt * 16 + lr) * 64 + slot * 8];
                    #pragma unroll
                    for (int u = 0; u < 4; ++u)
                        st[u] = __builtin_amdgcn_mfma_f32_16x16x32_bf16(kf, qf[u][c], st[u], 0, 0, 0);
                }
                #pragma unroll
                for (int u = 0; u < 4; ++u) {
                    float e0 = __builtin_amdgcn_exp2f(st[u][0]);
                    float e1 = __builtin_amdgcn_exp2f(st[u][1]);
                    float e2 = __builtin_amdgcn_exp2f(st[u][2]);
                    float e3 = __builtin_amdgcn_exp2f(st[u][3]);
                    pk[u][ml][0] = pack_bf2(e1, e0);
                    pk[u][ml][1] = pack_bf2(e3, e2);
                }
            }

            // --- lane exchange P^T -> PV B-frags (pure VALU permlane) ---
            bf16x8 pb[4];
            #pragma unroll
            for (int u = 0; u < 4; ++u) {
                uint2v a0 = __builtin_amdgcn_permlane32_swap(pk[u][0][0], pk[u][1][0], false, false);
                uint2v b0 = __builtin_amdgcn_permlane16_swap(a0[0], a0[1], false, false);
                uint2v a1 = __builtin_amdgcn_permlane32_swap(pk[u][0][1], pk[u][1][1], false, false);
                uint2v b1 = __builtin_amdgcn_permlane16_swap(a1[0], a1[1], false, false);
                int4 wv;
                wv.x = (int)b0[0];
                wv.y = (int)b1[0];
                wv.z = (int)b0[1];
                wv.w = (int)b1[1];
                pb[u] = *(bf16x8*)&wv;
            }

            // --- PV: O^T += V^T · P^T  (+ denominator row-sum) ---
            #pragma unroll
            for (int u = 0; u < 4; ++u)
                lsum[u] = __builtin_amdgcn_mfma_f32_16x16x32_bf16(onesf, pb[u], lsum[u], 0, 0, 0);
            #pragma unroll
            for (int jd = 0; jd < 4; ++jd) {
                const int slot = (kc * 4 + q4) ^ lr7;
                bf16x8 vf = *(const bf16x8*)&Vts[cur][(jd * 16 + lr) * 64 + slot * 8];
                #pragma unroll
                for (int u = 0; u < 4; ++u)
                    o[u][jd] = __builtin_amdgcn_mfma_f32_16x16x32_bf16(vf, pb[u], o[u][jd], 0, 0, 0);
            }
        }
        cur ^= 1;
    }

    #pragma unroll
    for (int u = 0; u < 4; ++u) {
        const float inv = __builtin_amdgcn_rcpf(lsum[u][0]);
        const size_t rowO = (size_t)(qrow0 + u * 16 + lr);
        #pragma unroll
        for (int jd = 0; jd < 4; ++jd) {
            ushortx4 v;
            #pragma unroll
            for (int p = 0; p < 4; ++p)
                v[p] = f2bf(o[u][jd][p] * inv);
            *(ushortx4*)&HC[rowO * 1024 + h * 64 + jd * 16 + q4 * 4] = v;
        }
    }
}

// ---------------------------------------------------------------------------
extern "C" void kernel_launch(void* const* d_in, const int* in_sizes, int n_in,
                              void* d_out, int out_size, void* d_ws, size_t ws_size,
                              hipStream_t stream)
{
    const float* x  = (const float*)d_in[0];
    const float* Wq = (const float*)d_in[1];
    const float* Wk = (const float*)d_in[2];
    const float* Wv = (const float*)d_in[3];
    const float* Wo = (const float*)d_in[4];
    float* out = (float*)d_out;

    char* ws = (char*)d_ws;
    unsigned short* XB    = (unsigned short*)(ws);              // 16777216 (aliases HC)
    unsigned short* HC    = (unsigned short*)(ws);
    unsigned short* WQKVT = (unsigned short*)(ws + 16777216);   // 6291456
    unsigned short* WOT   = (unsigned short*)(ws + 23068672);   // 2097152
    unsigned short* QK    = (unsigned short*)(ws + 25165824);   // 33554432
    unsigned short* VT    = (unsigned short*)(ws + 58720256);   // 16777216
    // total ws: 75497472 B (~72 MiB)

    pack_all<<<6144, 256, 0, stream>>>(x, Wq, Wk, Wv, Wo, XB, WQKVT, WOT);
    // QK projection (N=2048, swapped/vec stores) + V projection (N=1024, -> VT)
    gemm_bt<1, 128><<<dim3(16, 64), 256, 0, stream>>>(XB, WQKVT, QK, nullptr, 8192, 2048, 1024, 0);
    gemm_bt<2, 128><<<dim3(8, 64), 256, 0, stream>>>(XB, WQKVT + (size_t)2048 * 1024, nullptr, VT, 8192, 1024, 1024, 0);
    attn_flash<<<dim3(64, 8), 256, 0, stream>>>(QK, VT, HC);
    gemm_bt<0, 64><<<dim3(16, 64), 256, 0, stream>>>(HC, WOT, out, nullptr, 8192, 1024, 1024, 1024);
}

// Round 6
// 294.930 us; speedup vs baseline: 1.0534x; 1.0534x over previous
//
#include <hip/hip_runtime.h>

// MultiHeadAttention: B=4, S=2048, D=1024, H=16, dk=dv=64.
// Inputs fp32, output fp32; compute bf16 MFMA.
// R9: attention computes S^T = K·Q^T so P^T exits MFMA in a layout reachable
// from the PV B-operand by a pure lane permutation -- no P LDS round-trip.
// R10: attn VALU diet: builtin exp2, ones-MFMA denominator, v_perm pack.
// R11: 64 q-rows/wave. NEUTRAL -> ds_read BW was not binding.
// R12: ds_bpermute -> permlane32/16_swap: conflicts 8.4M->0, attn 112->83us.
// R13: gemm_bt double-buffered, 1 barrier/K-step (-9us).
// R14: operand-swap (free D^T) -> vector epilogue stores.  REGRESSED +25us:
// the bundled QKV launch split (1536 blocks @5/CU -> 1024@4/CU + 512@2/CU,
// serialized) cut the concurrency that hides the 2-phase loop's drain.
// R15: recombine QKV into one (24,64) launch; keep vector stores.  swap is
// block-uniform (n0<2048): two compile-time K-loop copies behind a uniform
// branch -- QK blocks store D^T as ushortx4 rows, V blocks store VT [d][s].

typedef __attribute__((ext_vector_type(8))) short bf16x8;   // 8 bf16 = 4 VGPRs
typedef __attribute__((ext_vector_type(4))) float f32x4;
typedef __attribute__((ext_vector_type(4))) unsigned short ushortx4;
typedef __attribute__((ext_vector_type(2))) unsigned int uint2v;

template<bool B> struct BoolC { static constexpr bool v = B; };

__device__ __forceinline__ unsigned short f2bf(float x) {   // RNE
    unsigned int u = __float_as_uint(x);
    u += 0x7FFFu + ((u >> 16) & 1u);
    return (unsigned short)(u >> 16);
}
// pack two floats as truncated bf16 pair: [hi.bf16 : lo.bf16] -- v_perm_b32
__device__ __forceinline__ unsigned int pack_bf2(float hi, float lo) {
    return __builtin_amdgcn_perm(__float_as_uint(hi), __float_as_uint(lo), 0x07060302u);
}

// async 16B global -> LDS (lds dest wave-uniform; HW adds lane*16)
__device__ __forceinline__ void gload_lds16(const unsigned short* g, unsigned short* lds) {
    __builtin_amdgcn_global_load_lds(
        (const __attribute__((address_space(1))) unsigned int*)g,
        (__attribute__((address_space(3))) unsigned int*)lds,
        16, 0, 0);
}

// ---------------------------------------------------------------------------
// One merged pack kernel. Sections by blockIdx.x:
//  [0,4096):      XB  = bf16(x)
//  [4096,5632):   WQKVT[n][d] (Wq pre-scaled by 0.125*log2e)
//  [5632,6144):   WOT[n][k] = Wo[k][n]
__global__ __launch_bounds__(256) void pack_all(
    const float* __restrict__ x,
    const float* __restrict__ Wq,
    const float* __restrict__ Wk,
    const float* __restrict__ Wv,
    const float* __restrict__ Wo,
    unsigned short* __restrict__ XB,
    unsigned short* __restrict__ WQKVT,
    unsigned short* __restrict__ WOT)
{
    const int bid = blockIdx.x;
    bf16x8 v;
    if (bid < 4096) {
        size_t base = ((size_t)bid * 256 + threadIdx.x) * 8;
        float4 f0 = *(const float4*)&x[base];
        float4 f1 = *(const float4*)&x[base + 4];
        v[0] = f2bf(f0.x); v[1] = f2bf(f0.y); v[2] = f2bf(f0.z); v[3] = f2bf(f0.w);
        v[4] = f2bf(f1.x); v[5] = f2bf(f1.y); v[6] = f2bf(f1.z); v[7] = f2bf(f1.w);
        *(bf16x8*)&XB[base] = v;
    } else if (bid < 5632) {
        int i = (bid - 4096) * 256 + threadIdx.x;
        int d0 = (i * 8) & 1023;
        int n  = (i * 8) >> 10;
        int part = n >> 10;
        int hkk  = n & 1023;
        int h = hkk >> 6, kk = hkk & 63;
        const float* W = (part == 0) ? Wq : ((part == 1) ? Wk : Wv);
        float scale = (part == 0) ? 0.125f * 1.44269504088896f : 1.0f;
        #pragma unroll
        for (int e = 0; e < 8; ++e)
            v[e] = f2bf(W[(h << 16) + ((d0 + e) << 6) + kk] * scale);
        *(bf16x8*)&WQKVT[(size_t)n * 1024 + d0] = v;
    } else {
        int i = (bid - 5632) * 256 + threadIdx.x;
        int k0 = (i * 8) & 1023;
        int n  = (i * 8) >> 10;
        #pragma unroll
        for (int e = 0; e < 8; ++e)
            v[e] = f2bf(Wo[(size_t)(k0 + e) * 1024 + n]);
        *(bf16x8*)&WOT[(size_t)n * 1024 + k0] = v;
    }
}

// ---------------------------------------------------------------------------
// C = A[M][K] @ Bt[N][K]^T, A/Bt bf16 row-major, global_load_lds staging into
// double-buffered LDS, 1 barrier per K-step (DMA t+1 in flight across compute t).
// CMODE 0: fp32 C, swapped operands -> float4 row stores (out projection).
// CMODE 1: combined QKV.  Block-uniform swap=(n0<2048): QK blocks use swapped
//          operands + ushortx4 row stores into QK; V blocks unswapped + VT
//          [d][s] stores.
// BN=128: 4 waves 2x2, 4x4 frags.  BN=64: 4 waves 4x1, 2x4 frags.
template<int CMODE, int BN>
__global__ __launch_bounds__(256) void gemm_bt(
    const unsigned short* __restrict__ A,
    const unsigned short* __restrict__ Bt,
    void* __restrict__ Cv,
    unsigned short* __restrict__ VT,
    int M, int N, int K, int ldc)
{
    __shared__ __align__(16) unsigned short As[2][128 * 32];
    __shared__ __align__(16) unsigned short Bs[2][BN * 32];
    const int m0 = blockIdx.y * 128;
    const int n0 = blockIdx.x * BN;
    const int tid  = threadIdx.x;
    const int w    = tid >> 6, lane = tid & 63;
    const int q4   = lane >> 4, lr  = lane & 15;
    constexpr int MI = (BN == 128) ? 4 : 2;
    const int rowBase = (BN == 128) ? (w >> 1) * 64 : w * 32;
    const int colBase = (BN == 128) ? (w & 1) * 64 : 0;

    const int ch   = tid & 3;
    const int row0 = tid >> 2;
    const int ldsOff = w * 512;   // halfwords; HW adds lane*16B

    const unsigned short* aP0 = &A [(size_t)(m0 + row0)      * K + ch * 8];
    const unsigned short* aP1 = &A [(size_t)(m0 + row0 + 64) * K + ch * 8];
    const unsigned short* bP0 = &Bt[(size_t)(n0 + row0)      * K + ch * 8];
    const unsigned short* bP1 = (BN == 128)
        ? &Bt[(size_t)(n0 + row0 + 64) * K + ch * 8] : nullptr;

    auto dma = [&](int buf, int k0) {
        gload_lds16(aP0 + k0, &As[buf][ldsOff]);
        gload_lds16(aP1 + k0, &As[buf][2048 + ldsOff]);
        gload_lds16(bP0 + k0, &Bs[buf][ldsOff]);
        if (BN == 128)
            gload_lds16(bP1 + k0, &Bs[buf][2048 + ldsOff]);
    };

    f32x4 acc[MI][4] = {};
    dma(0, 0);

    // swap: D computed transposed in-register (thread: row=lr, cols=q4*4+p)
    const bool swapSel = (CMODE == 0) || (n0 < 2048);

    auto mainloop = [&](auto SW) {
        constexpr bool S = decltype(SW)::v;
        int cur = 0;
        for (int k0 = 0; k0 < K; k0 += 32) {
            __syncthreads();                          // drains DMA(k0)
            if (k0 + 32 < K) dma(cur ^ 1, k0 + 32);   // in flight during compute

            bf16x8 af[MI], bfv[4];
            #pragma unroll
            for (int i = 0; i < MI; ++i)
                af[i] = *(const bf16x8*)&As[cur][(rowBase + i * 16 + lr) * 32 + q4 * 8];
            #pragma unroll
            for (int j = 0; j < 4; ++j)
                bfv[j] = *(const bf16x8*)&Bs[cur][(colBase + j * 16 + lr) * 32 + q4 * 8];
            #pragma unroll
            for (int i = 0; i < MI; ++i)
                #pragma unroll
                for (int j = 0; j < 4; ++j) {
                    if constexpr (S)
                        acc[i][j] = __builtin_amdgcn_mfma_f32_16x16x32_bf16(bfv[j], af[i], acc[i][j], 0, 0, 0);
                    else
                        acc[i][j] = __builtin_amdgcn_mfma_f32_16x16x32_bf16(af[i], bfv[j], acc[i][j], 0, 0, 0);
                }
            cur ^= 1;
        }
    };
    if (CMODE == 0 || swapSel) mainloop(BoolC<true>{});
    else                       mainloop(BoolC<false>{});

    #pragma unroll
    for (int i = 0; i < MI; ++i) {
        #pragma unroll
        for (int j = 0; j < 4; ++j) {
            if constexpr (CMODE == 0) {
                // swapped: row = ..+lr, cols = ..+q4*4+p  -> float4 store
                const int row = m0 + rowBase + i * 16 + lr;
                const int col = n0 + colBase + j * 16 + q4 * 4;
                float* C = (float*)Cv;
                float4 fv = { acc[i][j][0], acc[i][j][1], acc[i][j][2], acc[i][j][3] };
                *(float4*)&C[(size_t)row * ldc + col] = fv;
            } else {
                if (swapSel) {
                    // QK region, swapped frag -> ushortx4 row store
                    const int row = m0 + rowBase + i * 16 + lr;
                    const int col = n0 + colBase + j * 16 + q4 * 4;
                    unsigned short* C = (unsigned short*)Cv;
                    ushortx4 v;
                    #pragma unroll
                    for (int p = 0; p < 4; ++p) v[p] = f2bf(acc[i][j][p]);
                    *(ushortx4*)&C[(size_t)row * 2048 + col] = v;
                } else {
                    // V region, unswapped: row = s-dim (..+q4*4), col = h*64+d (..+lr)
                    const int row = m0 + rowBase + i * 16 + q4 * 4;
                    const int col = n0 + colBase + j * 16 + lr;
                    const int c2 = col - 2048;
                    const int hh = c2 >> 6, dd = c2 & 63;
                    const int bb = row >> 11, ss = row & 2047;
                    ushortx4 v;
                    #pragma unroll
                    for (int p = 0; p < 4; ++p) v[p] = f2bf(acc[i][j][p]);
                    *(ushortx4*)&VT[((size_t)(bb * 16 + hh) * 64 + dd) * 2048 + ss] = v;
                }
            }
        }
    }
}

// ---------------------------------------------------------------------------
// Flash attention, transposed-P scheme.  QK[8192][2048] bf16 (Q|K),
// VT[(b*16+h)*64+d][2048] bf16.  WG = (bh, 256-q block); wave w: 64 q as
// 4 subtiles u.  64-key tiles, K/V in XOR-swizzled stride-64 double buffers
// filled by global_load_lds; S^T = K·Q^T; P^T moved to PV B-frags via
// permlane32_swap + permlane16_swap (pure VALU, no LDS); O^T = V^T·P^T.
// Softmax denominator accumulated by a ones-A-frag MFMA.
__global__ __launch_bounds__(256, 2) void attn_flash(
    const unsigned short* __restrict__ QK,
    const unsigned short* __restrict__ VT,
    unsigned short* __restrict__ HC)        // [8192][1024] bf16
{
    const int bh  = blockIdx.x;   // b*16+h  (fastest dim -> XCD-pinned K/V reuse)
    const int qb  = blockIdx.y;   // 0..7
    const int b   = bh >> 4, h = bh & 15;
    const int tid = threadIdx.x;
    const int w   = tid >> 6, lane = tid & 63;
    const int q4  = lane >> 4, lr  = lane & 15;

    __shared__ __align__(16) unsigned short Ks [2][64 * 64];   // [key][dk] swizzled
    __shared__ __align__(16) unsigned short Vts[2][64 * 64];   // [d][key]  swizzled

    // DMA mapping: round R covers rows R*32+(tid>>3), chunk slot tid&7.
    const int drow   = tid >> 3;                       // 0..31
    const int gchunk = (tid & 7) ^ (drow & 7);         // global chunk for slot tid&7
    const unsigned short* Kg = QK + (size_t)(b * 2048) * 2048 + 1024 + h * 64;
    const unsigned short* Vg = VT + (size_t)bh * 64 * 2048;
    // running global pointers (advance per 64-key tile)
    const unsigned short* kP0 = Kg + (size_t)(drow)      * 2048 + gchunk * 8;
    const unsigned short* kP1 = Kg + (size_t)(drow + 32) * 2048 + gchunk * 8;
    const unsigned short* vP0 = Vg + (size_t)(drow)      * 2048 + gchunk * 8;
    const unsigned short* vP1 = Vg + (size_t)(drow + 32) * 2048 + gchunk * 8;
    const int ldsOff = w * 512;                        // halfwords; +lane*8 by HW

    auto dma = [&](int buf, int t) {
        gload_lds16(kP0 + (size_t)t * 131072, &Ks [buf][ldsOff]);
        gload_lds16(kP1 + (size_t)t * 131072, &Ks [buf][2048 + ldsOff]);
        gload_lds16(vP0 + t * 64,             &Vts[buf][ldsOff]);
        gload_lds16(vP1 + t * 64,             &Vts[buf][2048 + ldsOff]);
    };

    dma(0, 0);

    const int qrow0 = b * 2048 + qb * 256 + w * 64;
    bf16x8 qf[4][2];   // B-frag of Q^T == A-frag of Q: Q[q=lr][dk=c*32+q4*8+j]
    #pragma unroll
    for (int u = 0; u < 4; ++u)
        #pragma unroll
        for (int c = 0; c < 2; ++c)
            qf[u][c] = *(const bf16x8*)&QK[(size_t)(qrow0 + u * 16 + lr) * 2048
                                           + h * 64 + c * 32 + q4 * 8];

    const int lr7 = lr & 7;

    // ones A-fragment (bf16 1.0) for denominator row-sum MFMA
    const short oneb = (short)0x3F80;
    const bf16x8 onesf = { oneb, oneb, oneb, oneb, oneb, oneb, oneb, oneb };

    f32x4 o[4][4] = {};      // O^T[d=jd*16+q4*4+p][q=u*16+lr]
    f32x4 lsum[4] = {};      // denominator: all rows equal = sum_k P^T[k][q=lr]
    int cur = 0;

    for (int t = 0; t < 32; ++t) {
        __syncthreads();                       // drains DMA(t) -> buf[cur] ready
        if (t + 1 < 32) dma(cur ^ 1, t + 1);   // in flight during compute

        #pragma unroll
        for (int kc = 0; kc < 2; ++kc) {
            // --- S^T for this 32-key chunk (2 mt subtiles) ---
            unsigned int pk[4][2][2];          // packed P^T words [u][ml][i]
            #pragma unroll
            for (int ml = 0; ml < 2; ++ml) {
                const int mt = kc * 2 + ml;
                f32x4 st[4] = {};
                #pragma unroll
                for (int c = 0; c < 2; ++c) {
                    const int slot = (c * 4 + q4) ^ lr7;
                    bf16x8 kf = *(const bf16x8*)&Ks[cur][(mt * 16 + lr) * 64 + slot * 8];
                    #pragma unroll
                    for (int u = 0; u < 4; ++u)
                        st[u] = __builtin_amdgcn_mfma_f32_16x16x32_bf16(kf, qf[u][c], st[u], 0, 0, 0);
                }
                #pragma unroll
                for (int u = 0; u < 4; ++u) {
                    float e0 = __builtin_amdgcn_exp2f(st[u][0]);
                    float e1 = __builtin_amdgcn_exp2f(st[u][1]);
                    float e2 = __builtin_amdgcn_exp2f(st[u][2]);
                    float e3 = __builtin_amdgcn_exp2f(st[u][3]);
                    pk[u][ml][0] = pack_bf2(e1, e0);
                    pk[u][ml][1] = pack_bf2(e3, e2);
                }
            }

            // --- lane exchange P^T -> PV B-frags (pure VALU permlane) ---
            bf16x8 pb[4];
            #pragma unroll
            for (int u = 0; u < 4; ++u) {
                uint2v a0 = __builtin_amdgcn_permlane32_swap(pk[u][0][0], pk[u][1][0], false, false);
                uint2v b0 = __builtin_amdgcn_permlane16_swap(a0[0], a0[1], false, false);
                uint2v a1 = __builtin_amdgcn_permlane32_swap(pk[u][0][1], pk[u][1][1], false, false);
                uint2v b1 = __builtin_amdgcn_permlane16_swap(a1[0], a1[1], false, false);
                int4 wv;
                wv.x = (int)b0[0];
                wv.y = (int)b1[0];
                wv.z = (int)b0[1];
                wv.w = (int)b1[1];
                pb[u] = *(bf16x8*)&wv;
            }

            // --- PV: O^T += V^T · P^T  (+ denominator row-sum) ---
            #pragma unroll
            for (int u = 0; u < 4; ++u)
                lsum[u] = __builtin_amdgcn_mfma_f32_16x16x32_bf16(onesf, pb[u], lsum[u], 0, 0, 0);
            #pragma unroll
            for (int jd = 0; jd < 4; ++jd) {
                const int slot = (kc * 4 + q4) ^ lr7;
                bf16x8 vf = *(const bf16x8*)&Vts[cur][(jd * 16 + lr) * 64 + slot * 8];
                #pragma unroll
                for (int u = 0; u < 4; ++u)
                    o[u][jd] = __builtin_amdgcn_mfma_f32_16x16x32_bf16(vf, pb[u], o[u][jd], 0, 0, 0);
            }
        }
        cur ^= 1;
    }

    #pragma unroll
    for (int u = 0; u < 4; ++u) {
        const float inv = __builtin_amdgcn_rcpf(lsum[u][0]);
        const size_t rowO = (size_t)(qrow0 + u * 16 + lr);
        #pragma unroll
        for (int jd = 0; jd < 4; ++jd) {
            ushortx4 v;
            #pragma unroll
            for (int p = 0; p < 4; ++p)
                v[p] = f2bf(o[u][jd][p] * inv);
            *(ushortx4*)&HC[rowO * 1024 + h * 64 + jd * 16 + q4 * 4] = v;
        }
    }
}

// ---------------------------------------------------------------------------
extern "C" void kernel_launch(void* const* d_in, const int* in_sizes, int n_in,
                              void* d_out, int out_size, void* d_ws, size_t ws_size,
                              hipStream_t stream)
{
    const float* x  = (const float*)d_in[0];
    const float* Wq = (const float*)d_in[1];
    const float* Wk = (const float*)d_in[2];
    const float* Wv = (const float*)d_in[3];
    const float* Wo = (const float*)d_in[4];
    float* out = (float*)d_out;

    char* ws = (char*)d_ws;
    unsigned short* XB    = (unsigned short*)(ws);              // 16777216 (aliases HC)
    unsigned short* HC    = (unsigned short*)(ws);
    unsigned short* WQKVT = (unsigned short*)(ws + 16777216);   // 6291456
    unsigned short* WOT   = (unsigned short*)(ws + 23068672);   // 2097152
    unsigned short* QK    = (unsigned short*)(ws + 25165824);   // 33554432
    unsigned short* VT    = (unsigned short*)(ws + 58720256);   // 16777216
    // total ws: 75497472 B (~72 MiB)

    pack_all<<<6144, 256, 0, stream>>>(x, Wq, Wk, Wv, Wo, XB, WQKVT, WOT);
    gemm_bt<1, 128><<<dim3(24, 64), 256, 0, stream>>>(XB, WQKVT, QK, VT, 8192, 3072, 1024, 0);
    attn_flash<<<dim3(64, 8), 256, 0, stream>>>(QK, VT, HC);
    gemm_bt<0, 64><<<dim3(16, 64), 256, 0, stream>>>(HC, WOT, out, nullptr, 8192, 1024, 1024, 1024);
}

// Round 7
// 266.456 us; speedup vs baseline: 1.1659x; 1.1069x over previous
//
#include <hip/hip_runtime.h>

// MultiHeadAttention: B=4, S=2048, D=1024, H=16, dk=dv=64.
// Inputs fp32, output fp32; compute bf16 MFMA.
// R9: attention computes S^T = K·Q^T so P^T exits MFMA in a layout reachable
// from the PV B-operand by a pure lane permutation -- no P LDS round-trip.
// R10: attn VALU diet: builtin exp2, ones-MFMA denominator, v_perm pack.
// R12: ds_bpermute -> permlane32/16_swap: conflicts 8.4M->0, attn 112->83us.
// R13: gemm_bt double-buffered, 1 barrier/K-step (-9us).  BEST GEMM config.
// R14/R15: vector-store epilogue bundles net-negative -> reverted to R13.
// R16: (a) pack_all W sections were stride-256B/4KB scalar loads (16x
// over-fetch): now LDS-transpose tiles, coalesced float4 in / bf16x8 out.
// (b) attn back to 32 q-rows/wave (grid 64x16, 4 waves/SIMD): R11's halved
// occupancy was neutral under ds_bpermute but now starves the
// QK->exp2->permlane->PV chain of interleaving waves (40+45=85% issue, rest
// stall).  All R12 wins kept.

typedef __attribute__((ext_vector_type(8))) short bf16x8;   // 8 bf16 = 4 VGPRs
typedef __attribute__((ext_vector_type(4))) float f32x4;
typedef __attribute__((ext_vector_type(4))) unsigned short ushortx4;
typedef __attribute__((ext_vector_type(2))) unsigned int uint2v;

__device__ __forceinline__ unsigned short f2bf(float x) {   // RNE
    unsigned int u = __float_as_uint(x);
    u += 0x7FFFu + ((u >> 16) & 1u);
    return (unsigned short)(u >> 16);
}
// pack two floats as truncated bf16 pair: [hi.bf16 : lo.bf16] -- v_perm_b32
__device__ __forceinline__ unsigned int pack_bf2(float hi, float lo) {
    return __builtin_amdgcn_perm(__float_as_uint(hi), __float_as_uint(lo), 0x07060302u);
}

// async 16B global -> LDS (lds dest wave-uniform; HW adds lane*16)
__device__ __forceinline__ void gload_lds16(const unsigned short* g, unsigned short* lds) {
    __builtin_amdgcn_global_load_lds(
        (const __attribute__((address_space(1))) unsigned int*)g,
        (__attribute__((address_space(3))) unsigned int*)lds,
        16, 0, 0);
}

// ---------------------------------------------------------------------------
// One merged pack kernel. Sections by blockIdx.x:
//  [0,4096):      XB  = bf16(x)                       (coalesced, unchanged)
//  [4096,4480):   WQKVT[n][d]  via LDS-transposed tiles (Wq scaled)
//  [4480,4608):   WOT[n][k] = Wo[k][n] via LDS-transposed tiles
// Transpose tile = [128 r][64 c] fp32: coalesced float4 reads along c,
// lds[c][129*?] transpose, bf16x8 writes along r.
__global__ __launch_bounds__(256) void pack_all(
    const float* __restrict__ x,
    const float* __restrict__ Wq,
    const float* __restrict__ Wk,
    const float* __restrict__ Wv,
    const float* __restrict__ Wo,
    unsigned short* __restrict__ XB,
    unsigned short* __restrict__ WQKVT,
    unsigned short* __restrict__ WOT)
{
    const int bid = blockIdx.x;
    const int tid = threadIdx.x;
    if (bid < 4096) {
        bf16x8 v;
        size_t base = ((size_t)bid * 256 + tid) * 8;
        float4 f0 = *(const float4*)&x[base];
        float4 f1 = *(const float4*)&x[base + 4];
        v[0] = f2bf(f0.x); v[1] = f2bf(f0.y); v[2] = f2bf(f0.z); v[3] = f2bf(f0.w);
        v[4] = f2bf(f1.x); v[5] = f2bf(f1.y); v[6] = f2bf(f1.z); v[7] = f2bf(f1.w);
        *(bf16x8*)&XB[base] = v;
        return;
    }

    __shared__ float lds[64 * 129];
    const float* src;
    size_t outbase;
    float scale = 1.0f;
    int instride;
    unsigned short* outp;
    if (bid < 4480) {
        const int widx = bid - 4096;
        const int part = widx >> 7;           // 0..2 (q,k,v)
        const int rem  = widx & 127;
        const int h    = rem >> 3;            // 0..15
        const int chunk = rem & 7;            // d-chunk of 128
        const float* W = (part == 0) ? Wq : ((part == 1) ? Wk : Wv);
        src = W + h * 65536 + chunk * 8192;   // [128 d][64 kk], row stride 64
        instride = 64;
        outbase = ((size_t)(part * 1024 + h * 64)) * 1024 + chunk * 128;
        if (part == 0) scale = 0.125f * 1.44269504088896f;
        outp = WQKVT;
    } else {
        const int oidx = bid - 4480;
        const int kc = oidx >> 4;             // k-chunk of 128 (0..7)
        const int nc = oidx & 15;             // n-chunk of 64  (0..15)
        src = Wo + (size_t)kc * 128 * 1024 + nc * 64;   // [128 k][64 n], stride 1024
        instride = 1024;
        outbase = (size_t)(nc * 64) * 1024 + kc * 128;
        outp = WOT;
    }

    // read phase: [128 r][64 c] tile -> lds[c*129 + r]
    const int r0 = tid >> 4;                  // 0..15
    const int c4 = (tid & 15) * 4;            // 0,4,..,60
    #pragma unroll
    for (int cc = 0; cc < 8; ++cc) {
        const int r = cc * 16 + r0;
        float4 f = *(const float4*)&src[(size_t)r * instride + c4];
        lds[(c4 + 0) * 129 + r] = f.x * scale;
        lds[(c4 + 1) * 129 + r] = f.y * scale;
        lds[(c4 + 2) * 129 + r] = f.z * scale;
        lds[(c4 + 3) * 129 + r] = f.w * scale;
    }
    __syncthreads();

    // write phase: 64 out-rows (c), 128 bf16 each
    const int c = tid >> 2;                   // 0..63
    const int s = tid & 3;                    // 0..3
    #pragma unroll
    for (int j = 0; j < 4; ++j) {
        bf16x8 v;
        #pragma unroll
        for (int e = 0; e < 8; ++e)
            v[e] = f2bf(lds[c * 129 + s * 32 + j * 8 + e]);
        *(bf16x8*)&outp[outbase + (size_t)c * 1024 + s * 32 + j * 8] = v;
    }
}

// ---------------------------------------------------------------------------
// C = A[M][K] @ Bt[N][K]^T, A/Bt bf16 row-major, global_load_lds staging into
// double-buffered LDS, 1 barrier per K-step (DMA t+1 in flight across compute t).
// CMODE 0: C fp32 ldc.  CMODE 1: QKV split (QK bf16 / VT transposed).
// BN=128: 4 waves 2x2, 4x4 frags.  BN=64: 4 waves 4x1, 2x4 frags.
template<int CMODE, int BN>
__global__ __launch_bounds__(256) void gemm_bt(
    const unsigned short* __restrict__ A,
    const unsigned short* __restrict__ Bt,
    void* __restrict__ Cv,
    unsigned short* __restrict__ VT,
    int M, int N, int K, int ldc)
{
    __shared__ __align__(16) unsigned short As[2][128 * 32];
    __shared__ __align__(16) unsigned short Bs[2][BN * 32];
    const int m0 = blockIdx.y * 128;
    const int n0 = blockIdx.x * BN;
    const int tid  = threadIdx.x;
    const int w    = tid >> 6, lane = tid & 63;
    const int q4   = lane >> 4, lr  = lane & 15;
    constexpr int MI = (BN == 128) ? 4 : 2;
    const int rowBase = (BN == 128) ? (w >> 1) * 64 : w * 32;
    const int colBase = (BN == 128) ? (w & 1) * 64 : 0;

    const int ch   = tid & 3;
    const int row0 = tid >> 2;
    const int ldsOff = w * 512;   // halfwords; HW adds lane*16B

    const unsigned short* aP0 = &A [(size_t)(m0 + row0)      * K + ch * 8];
    const unsigned short* aP1 = &A [(size_t)(m0 + row0 + 64) * K + ch * 8];
    const unsigned short* bP0 = &Bt[(size_t)(n0 + row0)      * K + ch * 8];
    const unsigned short* bP1 = (BN == 128)
        ? &Bt[(size_t)(n0 + row0 + 64) * K + ch * 8] : nullptr;

    auto dma = [&](int buf, int k0) {
        gload_lds16(aP0 + k0, &As[buf][ldsOff]);
        gload_lds16(aP1 + k0, &As[buf][2048 + ldsOff]);
        gload_lds16(bP0 + k0, &Bs[buf][ldsOff]);
        if (BN == 128)
            gload_lds16(bP1 + k0, &Bs[buf][2048 + ldsOff]);
    };

    f32x4 acc[MI][4] = {};
    dma(0, 0);
    int cur = 0;

    for (int k0 = 0; k0 < K; k0 += 32) {
        __syncthreads();                          // drains DMA(k0) -> buf[cur] ready
        if (k0 + 32 < K) dma(cur ^ 1, k0 + 32);   // in flight during compute

        bf16x8 af[MI], bfv[4];
        #pragma unroll
        for (int i = 0; i < MI; ++i)
            af[i] = *(const bf16x8*)&As[cur][(rowBase + i * 16 + lr) * 32 + q4 * 8];
        #pragma unroll
        for (int j = 0; j < 4; ++j)
            bfv[j] = *(const bf16x8*)&Bs[cur][(colBase + j * 16 + lr) * 32 + q4 * 8];
        #pragma unroll
        for (int i = 0; i < MI; ++i)
            #pragma unroll
            for (int j = 0; j < 4; ++j)
                acc[i][j] = __builtin_amdgcn_mfma_f32_16x16x32_bf16(af[i], bfv[j], acc[i][j], 0, 0, 0);
        cur ^= 1;
    }

    #pragma unroll
    for (int i = 0; i < MI; ++i) {
        const int row = m0 + rowBase + i * 16 + q4 * 4;
        #pragma unroll
        for (int j = 0; j < 4; ++j) {
            const int col = n0 + colBase + j * 16 + lr;
            if (CMODE == 0) {
                float* C = (float*)Cv;
                #pragma unroll
                for (int p = 0; p < 4; ++p)
                    C[(size_t)(row + p) * ldc + col] = acc[i][j][p];
            } else {
                if (col < 2048) {
                    unsigned short* C = (unsigned short*)Cv;
                    #pragma unroll
                    for (int p = 0; p < 4; ++p)
                        C[(size_t)(row + p) * 2048 + col] = f2bf(acc[i][j][p]);
                } else {
                    const int c2 = col - 2048;
                    const int hh = c2 >> 6, dd = c2 & 63;
                    const int bb = row >> 11, ss = row & 2047;
                    ushortx4 v;
                    #pragma unroll
                    for (int p = 0; p < 4; ++p) v[p] = f2bf(acc[i][j][p]);
                    *(ushortx4*)&VT[((size_t)(bb * 16 + hh) * 64 + dd) * 2048 + ss] = v;
                }
            }
        }
    }
}

// ---------------------------------------------------------------------------
// Flash attention, transposed-P scheme.  QK[8192][2048] bf16 (Q|K),
// VT[(b*16+h)*64+d][2048] bf16.  WG = (bh, 128-q block); wave w: 32 q as
// 2 subtiles u.  64-key tiles, K/V in XOR-swizzled stride-64 double buffers
// filled by global_load_lds; S^T = K·Q^T; P^T moved to PV B-frags via
// permlane32_swap + permlane16_swap (pure VALU, no LDS); O^T = V^T·P^T.
// Softmax denominator accumulated by a ones-A-frag MFMA.
__global__ __launch_bounds__(256, 4) void attn_flash(
    const unsigned short* __restrict__ QK,
    const unsigned short* __restrict__ VT,
    unsigned short* __restrict__ HC)        // [8192][1024] bf16
{
    const int bh  = blockIdx.x;   // b*16+h  (fastest dim -> XCD-pinned K/V reuse)
    const int qb  = blockIdx.y;   // 0..15
    const int b   = bh >> 4, h = bh & 15;
    const int tid = threadIdx.x;
    const int w   = tid >> 6, lane = tid & 63;
    const int q4  = lane >> 4, lr  = lane & 15;

    __shared__ __align__(16) unsigned short Ks [2][64 * 64];   // [key][dk] swizzled
    __shared__ __align__(16) unsigned short Vts[2][64 * 64];   // [d][key]  swizzled

    // DMA mapping: round R covers rows R*32+(tid>>3), chunk slot tid&7.
    const int drow   = tid >> 3;                       // 0..31
    const int gchunk = (tid & 7) ^ (drow & 7);         // global chunk for slot tid&7
    const unsigned short* Kg = QK + (size_t)(b * 2048) * 2048 + 1024 + h * 64;
    const unsigned short* Vg = VT + (size_t)bh * 64 * 2048;
    // running global pointers (advance per 64-key tile)
    const unsigned short* kP0 = Kg + (size_t)(drow)      * 2048 + gchunk * 8;
    const unsigned short* kP1 = Kg + (size_t)(drow + 32) * 2048 + gchunk * 8;
    const unsigned short* vP0 = Vg + (size_t)(drow)      * 2048 + gchunk * 8;
    const unsigned short* vP1 = Vg + (size_t)(drow + 32) * 2048 + gchunk * 8;
    const int ldsOff = w * 512;                        // halfwords; +lane*8 by HW

    auto dma = [&](int buf, int t) {
        gload_lds16(kP0 + (size_t)t * 131072, &Ks [buf][ldsOff]);
        gload_lds16(kP1 + (size_t)t * 131072, &Ks [buf][2048 + ldsOff]);
        gload_lds16(vP0 + t * 64,             &Vts[buf][ldsOff]);
        gload_lds16(vP1 + t * 64,             &Vts[buf][2048 + ldsOff]);
    };

    dma(0, 0);

    const int qrow0 = b * 2048 + qb * 128 + w * 32;
    bf16x8 qf[2][2];   // B-frag of Q^T == A-frag of Q: Q[q=lr][dk=c*32+q4*8+j]
    #pragma unroll
    for (int u = 0; u < 2; ++u)
        #pragma unroll
        for (int c = 0; c < 2; ++c)
            qf[u][c] = *(const bf16x8*)&QK[(size_t)(qrow0 + u * 16 + lr) * 2048
                                           + h * 64 + c * 32 + q4 * 8];

    const int lr7 = lr & 7;

    // ones A-fragment (bf16 1.0) for denominator row-sum MFMA
    const short oneb = (short)0x3F80;
    const bf16x8 onesf = { oneb, oneb, oneb, oneb, oneb, oneb, oneb, oneb };

    f32x4 o[2][4] = {};      // O^T[d=jd*16+q4*4+p][q=u*16+lr]
    f32x4 lsum[2] = {};      // denominator: all rows equal = sum_k P^T[k][q=lr]
    int cur = 0;

    for (int t = 0; t < 32; ++t) {
        __syncthreads();                       // drains DMA(t) -> buf[cur] ready
        if (t + 1 < 32) dma(cur ^ 1, t + 1);   // in flight during compute

        #pragma unroll
        for (int kc = 0; kc < 2; ++kc) {
            // --- S^T for this 32-key chunk (2 mt subtiles) ---
            unsigned int pk[2][2][2];          // packed P^T words [u][ml][i]
            #pragma unroll
            for (int ml = 0; ml < 2; ++ml) {
                const int mt = kc * 2 + ml;
                f32x4 st[2] = {};
                #pragma unroll
                for (int c = 0; c < 2; ++c) {
                    const int slot = (c * 4 + q4) ^ lr7;
                    bf16x8 kf = *(const bf16x8*)&Ks[cur][(mt * 16 + lr) * 64 + slot * 8];
                    #pragma unroll
                    for (int u = 0; u < 2; ++u)
                        st[u] = __builtin_amdgcn_mfma_f32_16x16x32_bf16(kf, qf[u][c], st[u], 0, 0, 0);
                }
                #pragma unroll
                for (int u = 0; u < 2; ++u) {
                    float e0 = __builtin_amdgcn_exp2f(st[u][0]);
                    float e1 = __builtin_amdgcn_exp2f(st[u][1]);
                    float e2 = __builtin_amdgcn_exp2f(st[u][2]);
                    float e3 = __builtin_amdgcn_exp2f(st[u][3]);
                    pk[u][ml][0] = pack_bf2(e1, e0);
                    pk[u][ml][1] = pack_bf2(e3, e2);
                }
            }

            // --- lane exchange P^T -> PV B-frags (pure VALU permlane) ---
            // dest lane d=(q4,lr): dword i needs keys q4*8+2i,2i+1 of this
            // 32-key chunk.  X=pk[ml=0][i] (keys 0-15), Y=pk[ml=1][i] (16-31):
            //   a = permlane32_swap(X,Y):  a0={X.lo,Y.lo}, a1={X.hi,Y.hi}
            //   b = permlane16_swap(a0,a1): b0[d]=wv[2i], b1[d]=wv[2i+1]
            bf16x8 pb[2];
            #pragma unroll
            for (int u = 0; u < 2; ++u) {
                uint2v a0 = __builtin_amdgcn_permlane32_swap(pk[u][0][0], pk[u][1][0], false, false);
                uint2v b0 = __builtin_amdgcn_permlane16_swap(a0[0], a0[1], false, false);
                uint2v a1 = __builtin_amdgcn_permlane32_swap(pk[u][0][1], pk[u][1][1], false, false);
                uint2v b1 = __builtin_amdgcn_permlane16_swap(a1[0], a1[1], false, false);
                int4 wv;
                wv.x = (int)b0[0];
                wv.y = (int)b1[0];
                wv.z = (int)b0[1];
                wv.w = (int)b1[1];
                pb[u] = *(bf16x8*)&wv;
            }

            // --- PV: O^T += V^T · P^T  (+ denominator row-sum) ---
            #pragma unroll
            for (int u = 0; u < 2; ++u)
                lsum[u] = __builtin_amdgcn_mfma_f32_16x16x32_bf16(onesf, pb[u], lsum[u], 0, 0, 0);
            #pragma unroll
            for (int jd = 0; jd < 4; ++jd) {
                const int slot = (kc * 4 + q4) ^ lr7;
                bf16x8 vf = *(const bf16x8*)&Vts[cur][(jd * 16 + lr) * 64 + slot * 8];
                #pragma unroll
                for (int u = 0; u < 2; ++u)
                    o[u][jd] = __builtin_amdgcn_mfma_f32_16x16x32_bf16(vf, pb[u], o[u][jd], 0, 0, 0);
            }
        }
        cur ^= 1;
    }

    #pragma unroll
    for (int u = 0; u < 2; ++u) {
        const float inv = __builtin_amdgcn_rcpf(lsum[u][0]);
        const size_t rowO = (size_t)(qrow0 + u * 16 + lr);
        #pragma unroll
        for (int jd = 0; jd < 4; ++jd) {
            ushortx4 v;
            #pragma unroll
            for (int p = 0; p < 4; ++p)
                v[p] = f2bf(o[u][jd][p] * inv);
            *(ushortx4*)&HC[rowO * 1024 + h * 64 + jd * 16 + q4 * 4] = v;
        }
    }
}

// ---------------------------------------------------------------------------
extern "C" void kernel_launch(void* const* d_in, const int* in_sizes, int n_in,
                              void* d_out, int out_size, void* d_ws, size_t ws_size,
                              hipStream_t stream)
{
    const float* x  = (const float*)d_in[0];
    const float* Wq = (const float*)d_in[1];
    const float* Wk = (const float*)d_in[2];
    const float* Wv = (const float*)d_in[3];
    const float* Wo = (const float*)d_in[4];
    float* out = (float*)d_out;

    char* ws = (char*)d_ws;
    unsigned short* XB    = (unsigned short*)(ws);              // 16777216 (aliases HC)
    unsigned short* HC    = (unsigned short*)(ws);
    unsigned short* WQKVT = (unsigned short*)(ws + 16777216);   // 6291456
    unsigned short* WOT   = (unsigned short*)(ws + 23068672);   // 2097152
    unsigned short* QK    = (unsigned short*)(ws + 25165824);   // 33554432
    unsigned short* VT    = (unsigned short*)(ws + 58720256);   // 16777216
    // total ws: 75497472 B (~72 MiB)

    pack_all<<<4608, 256, 0, stream>>>(x, Wq, Wk, Wv, Wo, XB, WQKVT, WOT);
    gemm_bt<1, 128><<<dim3(24, 64), 256, 0, stream>>>(XB, WQKVT, QK, VT, 8192, 3072, 1024, 0);
    attn_flash<<<dim3(64, 16), 256, 0, stream>>>(QK, VT, HC);
    gemm_bt<0, 64><<<dim3(16, 64), 256, 0, stream>>>(HC, WOT, out, nullptr, 8192, 1024, 1024, 1024);
}

// Round 8
// 266.152 us; speedup vs baseline: 1.1673x; 1.0011x over previous
//
#include <hip/hip_runtime.h>

// MultiHeadAttention: B=4, S=2048, D=1024, H=16, dk=dv=64.
// Inputs fp32, output fp32; compute bf16 MFMA.
// R9: attention computes S^T = K·Q^T so P^T exits MFMA in a layout reachable
// from the PV B-operand by a pure lane permutation -- no P LDS round-trip.
// R10: attn VALU diet: builtin exp2, ones-MFMA denominator, v_perm pack.
// R12: ds_bpermute -> permlane32/16_swap: conflicts 8.4M->0, attn 112->83us.
// R13: gemm_bt double-buffered, 1 barrier/K-step (-9us).  BEST GEMM config.
// R14/R15: vector-store epilogue bundles net-negative -> reverted.
// R16: pack_all LDS-transpose (-19us); attn occupancy 2->4 waves/SIMD NEUTRAL
// (attn pinned ~82.5us by per-tile dep chain, not TLP).
// R17: ledger says GEMMs ~150us combined (~450 TF avg).  out-GEMM was BN=64:
// 128x64 block, 4 waves stacked 4x1 -> 8 MFMA per 8 ds_read (1:1) and B-frags
// read 4x redundantly.  Switch out projection to the BN=128 instantiation
// (64x64/wave, 16 MFMA : 8 ds_read), grid (8,64).  QKV/attn/pack untouched.

typedef __attribute__((ext_vector_type(8))) short bf16x8;   // 8 bf16 = 4 VGPRs
typedef __attribute__((ext_vector_type(4))) float f32x4;
typedef __attribute__((ext_vector_type(4))) unsigned short ushortx4;
typedef __attribute__((ext_vector_type(2))) unsigned int uint2v;

__device__ __forceinline__ unsigned short f2bf(float x) {   // RNE
    unsigned int u = __float_as_uint(x);
    u += 0x7FFFu + ((u >> 16) & 1u);
    return (unsigned short)(u >> 16);
}
// pack two floats as truncated bf16 pair: [hi.bf16 : lo.bf16] -- v_perm_b32
__device__ __forceinline__ unsigned int pack_bf2(float hi, float lo) {
    return __builtin_amdgcn_perm(__float_as_uint(hi), __float_as_uint(lo), 0x07060302u);
}

// async 16B global -> LDS (lds dest wave-uniform; HW adds lane*16)
__device__ __forceinline__ void gload_lds16(const unsigned short* g, unsigned short* lds) {
    __builtin_amdgcn_global_load_lds(
        (const __attribute__((address_space(1))) unsigned int*)g,
        (__attribute__((address_space(3))) unsigned int*)lds,
        16, 0, 0);
}

// ---------------------------------------------------------------------------
// One merged pack kernel. Sections by blockIdx.x:
//  [0,4096):      XB  = bf16(x)                       (coalesced)
//  [4096,4480):   WQKVT[n][d]  via LDS-transposed tiles (Wq scaled)
//  [4480,4608):   WOT[n][k] = Wo[k][n] via LDS-transposed tiles
// Transpose tile = [128 r][64 c] fp32: coalesced float4 reads along c,
// lds[c][129*?] transpose, bf16x8 writes along r.
__global__ __launch_bounds__(256) void pack_all(
    const float* __restrict__ x,
    const float* __restrict__ Wq,
    const float* __restrict__ Wk,
    const float* __restrict__ Wv,
    const float* __restrict__ Wo,
    unsigned short* __restrict__ XB,
    unsigned short* __restrict__ WQKVT,
    unsigned short* __restrict__ WOT)
{
    const int bid = blockIdx.x;
    const int tid = threadIdx.x;
    if (bid < 4096) {
        bf16x8 v;
        size_t base = ((size_t)bid * 256 + tid) * 8;
        float4 f0 = *(const float4*)&x[base];
        float4 f1 = *(const float4*)&x[base + 4];
        v[0] = f2bf(f0.x); v[1] = f2bf(f0.y); v[2] = f2bf(f0.z); v[3] = f2bf(f0.w);
        v[4] = f2bf(f1.x); v[5] = f2bf(f1.y); v[6] = f2bf(f1.z); v[7] = f2bf(f1.w);
        *(bf16x8*)&XB[base] = v;
        return;
    }

    __shared__ float lds[64 * 129];
    const float* src;
    size_t outbase;
    float scale = 1.0f;
    int instride;
    unsigned short* outp;
    if (bid < 4480) {
        const int widx = bid - 4096;
        const int part = widx >> 7;           // 0..2 (q,k,v)
        const int rem  = widx & 127;
        const int h    = rem >> 3;            // 0..15
        const int chunk = rem & 7;            // d-chunk of 128
        const float* W = (part == 0) ? Wq : ((part == 1) ? Wk : Wv);
        src = W + h * 65536 + chunk * 8192;   // [128 d][64 kk], row stride 64
        instride = 64;
        outbase = ((size_t)(part * 1024 + h * 64)) * 1024 + chunk * 128;
        if (part == 0) scale = 0.125f * 1.44269504088896f;
        outp = WQKVT;
    } else {
        const int oidx = bid - 4480;
        const int kc = oidx >> 4;             // k-chunk of 128 (0..7)
        const int nc = oidx & 15;             // n-chunk of 64  (0..15)
        src = Wo + (size_t)kc * 128 * 1024 + nc * 64;   // [128 k][64 n], stride 1024
        instride = 1024;
        outbase = (size_t)(nc * 64) * 1024 + kc * 128;
        outp = WOT;
    }

    // read phase: [128 r][64 c] tile -> lds[c*129 + r]
    const int r0 = tid >> 4;                  // 0..15
    const int c4 = (tid & 15) * 4;            // 0,4,..,60
    #pragma unroll
    for (int cc = 0; cc < 8; ++cc) {
        const int r = cc * 16 + r0;
        float4 f = *(const float4*)&src[(size_t)r * instride + c4];
        lds[(c4 + 0) * 129 + r] = f.x * scale;
        lds[(c4 + 1) * 129 + r] = f.y * scale;
        lds[(c4 + 2) * 129 + r] = f.z * scale;
        lds[(c4 + 3) * 129 + r] = f.w * scale;
    }
    __syncthreads();

    // write phase: 64 out-rows (c), 128 bf16 each
    const int c = tid >> 2;                   // 0..63
    const int s = tid & 3;                    // 0..3
    #pragma unroll
    for (int j = 0; j < 4; ++j) {
        bf16x8 v;
        #pragma unroll
        for (int e = 0; e < 8; ++e)
            v[e] = f2bf(lds[c * 129 + s * 32 + j * 8 + e]);
        *(bf16x8*)&outp[outbase + (size_t)c * 1024 + s * 32 + j * 8] = v;
    }
}

// ---------------------------------------------------------------------------
// C = A[M][K] @ Bt[N][K]^T, A/Bt bf16 row-major, global_load_lds staging into
// double-buffered LDS, 1 barrier per K-step (DMA t+1 in flight across compute t).
// CMODE 0: C fp32 ldc.  CMODE 1: QKV split (QK bf16 / VT transposed).
// BN=128: 4 waves 2x2, 4x4 frags.  BN=64: 4 waves 4x1, 2x4 frags.
template<int CMODE, int BN>
__global__ __launch_bounds__(256) void gemm_bt(
    const unsigned short* __restrict__ A,
    const unsigned short* __restrict__ Bt,
    void* __restrict__ Cv,
    unsigned short* __restrict__ VT,
    int M, int N, int K, int ldc)
{
    __shared__ __align__(16) unsigned short As[2][128 * 32];
    __shared__ __align__(16) unsigned short Bs[2][BN * 32];
    const int m0 = blockIdx.y * 128;
    const int n0 = blockIdx.x * BN;
    const int tid  = threadIdx.x;
    const int w    = tid >> 6, lane = tid & 63;
    const int q4   = lane >> 4, lr  = lane & 15;
    constexpr int MI = (BN == 128) ? 4 : 2;
    const int rowBase = (BN == 128) ? (w >> 1) * 64 : w * 32;
    const int colBase = (BN == 128) ? (w & 1) * 64 : 0;

    const int ch   = tid & 3;
    const int row0 = tid >> 2;
    const int ldsOff = w * 512;   // halfwords; HW adds lane*16B

    const unsigned short* aP0 = &A [(size_t)(m0 + row0)      * K + ch * 8];
    const unsigned short* aP1 = &A [(size_t)(m0 + row0 + 64) * K + ch * 8];
    const unsigned short* bP0 = &Bt[(size_t)(n0 + row0)      * K + ch * 8];
    const unsigned short* bP1 = (BN == 128)
        ? &Bt[(size_t)(n0 + row0 + 64) * K + ch * 8] : nullptr;

    auto dma = [&](int buf, int k0) {
        gload_lds16(aP0 + k0, &As[buf][ldsOff]);
        gload_lds16(aP1 + k0, &As[buf][2048 + ldsOff]);
        gload_lds16(bP0 + k0, &Bs[buf][ldsOff]);
        if (BN == 128)
            gload_lds16(bP1 + k0, &Bs[buf][2048 + ldsOff]);
    };

    f32x4 acc[MI][4] = {};
    dma(0, 0);
    int cur = 0;

    for (int k0 = 0; k0 < K; k0 += 32) {
        __syncthreads();                          // drains DMA(k0) -> buf[cur] ready
        if (k0 + 32 < K) dma(cur ^ 1, k0 + 32);   // in flight during compute

        bf16x8 af[MI], bfv[4];
        #pragma unroll
        for (int i = 0; i < MI; ++i)
            af[i] = *(const bf16x8*)&As[cur][(rowBase + i * 16 + lr) * 32 + q4 * 8];
        #pragma unroll
        for (int j = 0; j < 4; ++j)
            bfv[j] = *(const bf16x8*)&Bs[cur][(colBase + j * 16 + lr) * 32 + q4 * 8];
        #pragma unroll
        for (int i = 0; i < MI; ++i)
            #pragma unroll
            for (int j = 0; j < 4; ++j)
                acc[i][j] = __builtin_amdgcn_mfma_f32_16x16x32_bf16(af[i], bfv[j], acc[i][j], 0, 0, 0);
        cur ^= 1;
    }

    #pragma unroll
    for (int i = 0; i < MI; ++i) {
        const int row = m0 + rowBase + i * 16 + q4 * 4;
        #pragma unroll
        for (int j = 0; j < 4; ++j) {
            const int col = n0 + colBase + j * 16 + lr;
            if (CMODE == 0) {
                float* C = (float*)Cv;
                #pragma unroll
                for (int p = 0; p < 4; ++p)
                    C[(size_t)(row + p) * ldc + col] = acc[i][j][p];
            } else {
                if (col < 2048) {
                    unsigned short* C = (unsigned short*)Cv;
                    #pragma unroll
                    for (int p = 0; p < 4; ++p)
                        C[(size_t)(row + p) * 2048 + col] = f2bf(acc[i][j][p]);
                } else {
                    const int c2 = col - 2048;
                    const int hh = c2 >> 6, dd = c2 & 63;
                    const int bb = row >> 11, ss = row & 2047;
                    ushortx4 v;
                    #pragma unroll
                    for (int p = 0; p < 4; ++p) v[p] = f2bf(acc[i][j][p]);
                    *(ushortx4*)&VT[((size_t)(bb * 16 + hh) * 64 + dd) * 2048 + ss] = v;
                }
            }
        }
    }
}

// ---------------------------------------------------------------------------
// Flash attention, transposed-P scheme.  QK[8192][2048] bf16 (Q|K),
// VT[(b*16+h)*64+d][2048] bf16.  WG = (bh, 128-q block); wave w: 32 q as
// 2 subtiles u.  64-key tiles, K/V in XOR-swizzled stride-64 double buffers
// filled by global_load_lds; S^T = K·Q^T; P^T moved to PV B-frags via
// permlane32_swap + permlane16_swap (pure VALU, no LDS); O^T = V^T·P^T.
// Softmax denominator accumulated by a ones-A-frag MFMA.
__global__ __launch_bounds__(256, 4) void attn_flash(
    const unsigned short* __restrict__ QK,
    const unsigned short* __restrict__ VT,
    unsigned short* __restrict__ HC)        // [8192][1024] bf16
{
    const int bh  = blockIdx.x;   // b*16+h  (fastest dim -> XCD-pinned K/V reuse)
    const int qb  = blockIdx.y;   // 0..15
    const int b   = bh >> 4, h = bh & 15;
    const int tid = threadIdx.x;
    const int w   = tid >> 6, lane = tid & 63;
    const int q4  = lane >> 4, lr  = lane & 15;

    __shared__ __align__(16) unsigned short Ks [2][64 * 64];   // [key][dk] swizzled
    __shared__ __align__(16) unsigned short Vts[2][64 * 64];   // [d][key]  swizzled

    // DMA mapping: round R covers rows R*32+(tid>>3), chunk slot tid&7.
    const int drow   = tid >> 3;                       // 0..31
    const int gchunk = (tid & 7) ^ (drow & 7);         // global chunk for slot tid&7
    const unsigned short* Kg = QK + (size_t)(b * 2048) * 2048 + 1024 + h * 64;
    const unsigned short* Vg = VT + (size_t)bh * 64 * 2048;
    // running global pointers (advance per 64-key tile)
    const unsigned short* kP0 = Kg + (size_t)(drow)      * 2048 + gchunk * 8;
    const unsigned short* kP1 = Kg + (size_t)(drow + 32) * 2048 + gchunk * 8;
    const unsigned short* vP0 = Vg + (size_t)(drow)      * 2048 + gchunk * 8;
    const unsigned short* vP1 = Vg + (size_t)(drow + 32) * 2048 + gchunk * 8;
    const int ldsOff = w * 512;                        // halfwords; +lane*8 by HW

    auto dma = [&](int buf, int t) {
        gload_lds16(kP0 + (size_t)t * 131072, &Ks [buf][ldsOff]);
        gload_lds16(kP1 + (size_t)t * 131072, &Ks [buf][2048 + ldsOff]);
        gload_lds16(vP0 + t * 64,             &Vts[buf][ldsOff]);
        gload_lds16(vP1 + t * 64,             &Vts[buf][2048 + ldsOff]);
    };

    dma(0, 0);

    const int qrow0 = b * 2048 + qb * 128 + w * 32;
    bf16x8 qf[2][2];   // B-frag of Q^T == A-frag of Q: Q[q=lr][dk=c*32+q4*8+j]
    #pragma unroll
    for (int u = 0; u < 2; ++u)
        #pragma unroll
        for (int c = 0; c < 2; ++c)
            qf[u][c] = *(const bf16x8*)&QK[(size_t)(qrow0 + u * 16 + lr) * 2048
                                           + h * 64 + c * 32 + q4 * 8];

    const int lr7 = lr & 7;

    // ones A-fragment (bf16 1.0) for denominator row-sum MFMA
    const short oneb = (short)0x3F80;
    const bf16x8 onesf = { oneb, oneb, oneb, oneb, oneb, oneb, oneb, oneb };

    f32x4 o[2][4] = {};      // O^T[d=jd*16+q4*4+p][q=u*16+lr]
    f32x4 lsum[2] = {};      // denominator: all rows equal = sum_k P^T[k][q=lr]
    int cur = 0;

    for (int t = 0; t < 32; ++t) {
        __syncthreads();                       // drains DMA(t) -> buf[cur] ready
        if (t + 1 < 32) dma(cur ^ 1, t + 1);   // in flight during compute

        #pragma unroll
        for (int kc = 0; kc < 2; ++kc) {
            // --- S^T for this 32-key chunk (2 mt subtiles) ---
            unsigned int pk[2][2][2];          // packed P^T words [u][ml][i]
            #pragma unroll
            for (int ml = 0; ml < 2; ++ml) {
                const int mt = kc * 2 + ml;
                f32x4 st[2] = {};
                #pragma unroll
                for (int c = 0; c < 2; ++c) {
                    const int slot = (c * 4 + q4) ^ lr7;
                    bf16x8 kf = *(const bf16x8*)&Ks[cur][(mt * 16 + lr) * 64 + slot * 8];
                    #pragma unroll
                    for (int u = 0; u < 2; ++u)
                        st[u] = __builtin_amdgcn_mfma_f32_16x16x32_bf16(kf, qf[u][c], st[u], 0, 0, 0);
                }
                #pragma unroll
                for (int u = 0; u < 2; ++u) {
                    float e0 = __builtin_amdgcn_exp2f(st[u][0]);
                    float e1 = __builtin_amdgcn_exp2f(st[u][1]);
                    float e2 = __builtin_amdgcn_exp2f(st[u][2]);
                    float e3 = __builtin_amdgcn_exp2f(st[u][3]);
                    pk[u][ml][0] = pack_bf2(e1, e0);
                    pk[u][ml][1] = pack_bf2(e3, e2);
                }
            }

            // --- lane exchange P^T -> PV B-frags (pure VALU permlane) ---
            // dest lane d=(q4,lr): dword i needs keys q4*8+2i,2i+1 of this
            // 32-key chunk.  X=pk[ml=0][i] (keys 0-15), Y=pk[ml=1][i] (16-31):
            //   a = permlane32_swap(X,Y):  a0={X.lo,Y.lo}, a1={X.hi,Y.hi}
            //   b = permlane16_swap(a0,a1): b0[d]=wv[2i], b1[d]=wv[2i+1]
            bf16x8 pb[2];
            #pragma unroll
            for (int u = 0; u < 2; ++u) {
                uint2v a0 = __builtin_amdgcn_permlane32_swap(pk[u][0][0], pk[u][1][0], false, false);
                uint2v b0 = __builtin_amdgcn_permlane16_swap(a0[0], a0[1], false, false);
                uint2v a1 = __builtin_amdgcn_permlane32_swap(pk[u][0][1], pk[u][1][1], false, false);
                uint2v b1 = __builtin_amdgcn_permlane16_swap(a1[0], a1[1], false, false);
                int4 wv;
                wv.x = (int)b0[0];
                wv.y = (int)b1[0];
                wv.z = (int)b0[1];
                wv.w = (int)b1[1];
                pb[u] = *(bf16x8*)&wv;
            }

            // --- PV: O^T += V^T · P^T  (+ denominator row-sum) ---
            #pragma unroll
            for (int u = 0; u < 2; ++u)
                lsum[u] = __builtin_amdgcn_mfma_f32_16x16x32_bf16(onesf, pb[u], lsum[u], 0, 0, 0);
            #pragma unroll
            for (int jd = 0; jd < 4; ++jd) {
                const int slot = (kc * 4 + q4) ^ lr7;
                bf16x8 vf = *(const bf16x8*)&Vts[cur][(jd * 16 + lr) * 64 + slot * 8];
                #pragma unroll
                for (int u = 0; u < 2; ++u)
                    o[u][jd] = __builtin_amdgcn_mfma_f32_16x16x32_bf16(vf, pb[u], o[u][jd], 0, 0, 0);
            }
        }
        cur ^= 1;
    }

    #pragma unroll
    for (int u = 0; u < 2; ++u) {
        const float inv = __builtin_amdgcn_rcpf(lsum[u][0]);
        const size_t rowO = (size_t)(qrow0 + u * 16 + lr);
        #pragma unroll
        for (int jd = 0; jd < 4; ++jd) {
            ushortx4 v;
            #pragma unroll
            for (int p = 0; p < 4; ++p)
                v[p] = f2bf(o[u][jd][p] * inv);
            *(ushortx4*)&HC[rowO * 1024 + h * 64 + jd * 16 + q4 * 4] = v;
        }
    }
}

// ---------------------------------------------------------------------------
extern "C" void kernel_launch(void* const* d_in, const int* in_sizes, int n_in,
                              void* d_out, int out_size, void* d_ws, size_t ws_size,
                              hipStream_t stream)
{
    const float* x  = (const float*)d_in[0];
    const float* Wq = (const float*)d_in[1];
    const float* Wk = (const float*)d_in[2];
    const float* Wv = (const float*)d_in[3];
    const float* Wo = (const float*)d_in[4];
    float* out = (float*)d_out;

    char* ws = (char*)d_ws;
    unsigned short* XB    = (unsigned short*)(ws);              // 16777216 (aliases HC)
    unsigned short* HC    = (unsigned short*)(ws);
    unsigned short* WQKVT = (unsigned short*)(ws + 16777216);   // 6291456
    unsigned short* WOT   = (unsigned short*)(ws + 23068672);   // 2097152
    unsigned short* QK    = (unsigned short*)(ws + 25165824);   // 33554432
    unsigned short* VT    = (unsigned short*)(ws + 58720256);   // 16777216
    // total ws: 75497472 B (~72 MiB)

    pack_all<<<4608, 256, 0, stream>>>(x, Wq, Wk, Wv, Wo, XB, WQKVT, WOT);
    gemm_bt<1, 128><<<dim3(24, 64), 256, 0, stream>>>(XB, WQKVT, QK, VT, 8192, 3072, 1024, 0);
    attn_flash<<<dim3(64, 16), 256, 0, stream>>>(QK, VT, HC);
    gemm_bt<0, 128><<<dim3(8, 64), 256, 0, stream>>>(HC, WOT, out, nullptr, 8192, 1024, 1024, 1024);
}

// Round 9
// 260.911 us; speedup vs baseline: 1.1907x; 1.0201x over previous
//
#include <hip/hip_runtime.h>

// MultiHeadAttention: B=4, S=2048, D=1024, H=16, dk=dv=64.
// Inputs fp32, output fp32; compute bf16 MFMA.
// R9: attention computes S^T = K·Q^T so P^T exits MFMA in a layout reachable
// from the PV B-operand by a pure lane permutation -- no P LDS round-trip.
// R10: attn VALU diet: builtin exp2, ones-MFMA denominator, v_perm pack.
// R12: ds_bpermute -> permlane32/16_swap: conflicts 8.4M->0, attn 112->83us.
// R13: gemm_bt double-buffered, 1 barrier/K-step.
// R16: pack_all LDS-transpose (-19us); attn occupancy knobs NEUTRAL (attn
// pinned ~82.5us by per-tile dep chain).
// R17: out-GEMM BN=64->128 NEUTRAL -> out-GEMM not the drag.
// R18: QKV GEMM traffic arithmetic: A re-read 24x + B re-read 64x ~= 800MB,
// served from L3 because linear dispatch round-robins neighbors across XCDs.
// Add XCD-chunked swizzle (T1): each XCD owns 8 m-panels x all n-blocks ->
// A slice (2MB) L2-resident, ~halves L3 traffic.  (attn keeps its native
// bh%8 mapping: 8 heads' K/V = 4MB = exactly one XCD L2.)  Also T5 setprio
// around attn MFMA clusters (4 independent blocks/CU give the scheduler
// wave-phase diversity; revert if attn dur >= 83us).

typedef __attribute__((ext_vector_type(8))) short bf16x8;   // 8 bf16 = 4 VGPRs
typedef __attribute__((ext_vector_type(4))) float f32x4;
typedef __attribute__((ext_vector_type(4))) unsigned short ushortx4;
typedef __attribute__((ext_vector_type(2))) unsigned int uint2v;

__device__ __forceinline__ unsigned short f2bf(float x) {   // RNE
    unsigned int u = __float_as_uint(x);
    u += 0x7FFFu + ((u >> 16) & 1u);
    return (unsigned short)(u >> 16);
}
// pack two floats as truncated bf16 pair: [hi.bf16 : lo.bf16] -- v_perm_b32
__device__ __forceinline__ unsigned int pack_bf2(float hi, float lo) {
    return __builtin_amdgcn_perm(__float_as_uint(hi), __float_as_uint(lo), 0x07060302u);
}

// async 16B global -> LDS (lds dest wave-uniform; HW adds lane*16)
__device__ __forceinline__ void gload_lds16(const unsigned short* g, unsigned short* lds) {
    __builtin_amdgcn_global_load_lds(
        (const __attribute__((address_space(1))) unsigned int*)g,
        (__attribute__((address_space(3))) unsigned int*)lds,
        16, 0, 0);
}

// ---------------------------------------------------------------------------
// One merged pack kernel. Sections by blockIdx.x:
//  [0,4096):      XB  = bf16(x)                       (coalesced)
//  [4096,4480):   WQKVT[n][d]  via LDS-transposed tiles (Wq scaled)
//  [4480,4608):   WOT[n][k] = Wo[k][n] via LDS-transposed tiles
__global__ __launch_bounds__(256) void pack_all(
    const float* __restrict__ x,
    const float* __restrict__ Wq,
    const float* __restrict__ Wk,
    const float* __restrict__ Wv,
    const float* __restrict__ Wo,
    unsigned short* __restrict__ XB,
    unsigned short* __restrict__ WQKVT,
    unsigned short* __restrict__ WOT)
{
    const int bid = blockIdx.x;
    const int tid = threadIdx.x;
    if (bid < 4096) {
        bf16x8 v;
        size_t base = ((size_t)bid * 256 + tid) * 8;
        float4 f0 = *(const float4*)&x[base];
        float4 f1 = *(const float4*)&x[base + 4];
        v[0] = f2bf(f0.x); v[1] = f2bf(f0.y); v[2] = f2bf(f0.z); v[3] = f2bf(f0.w);
        v[4] = f2bf(f1.x); v[5] = f2bf(f1.y); v[6] = f2bf(f1.z); v[7] = f2bf(f1.w);
        *(bf16x8*)&XB[base] = v;
        return;
    }

    __shared__ float lds[64 * 129];
    const float* src;
    size_t outbase;
    float scale = 1.0f;
    int instride;
    unsigned short* outp;
    if (bid < 4480) {
        const int widx = bid - 4096;
        const int part = widx >> 7;           // 0..2 (q,k,v)
        const int rem  = widx & 127;
        const int h    = rem >> 3;            // 0..15
        const int chunk = rem & 7;            // d-chunk of 128
        const float* W = (part == 0) ? Wq : ((part == 1) ? Wk : Wv);
        src = W + h * 65536 + chunk * 8192;   // [128 d][64 kk], row stride 64
        instride = 64;
        outbase = ((size_t)(part * 1024 + h * 64)) * 1024 + chunk * 128;
        if (part == 0) scale = 0.125f * 1.44269504088896f;
        outp = WQKVT;
    } else {
        const int oidx = bid - 4480;
        const int kc = oidx >> 4;             // k-chunk of 128 (0..7)
        const int nc = oidx & 15;             // n-chunk of 64  (0..15)
        src = Wo + (size_t)kc * 128 * 1024 + nc * 64;   // [128 k][64 n], stride 1024
        instride = 1024;
        outbase = (size_t)(nc * 64) * 1024 + kc * 128;
        outp = WOT;
    }

    // read phase: [128 r][64 c] tile -> lds[c*129 + r]
    const int r0 = tid >> 4;                  // 0..15
    const int c4 = (tid & 15) * 4;            // 0,4,..,60
    #pragma unroll
    for (int cc = 0; cc < 8; ++cc) {
        const int r = cc * 16 + r0;
        float4 f = *(const float4*)&src[(size_t)r * instride + c4];
        lds[(c4 + 0) * 129 + r] = f.x * scale;
        lds[(c4 + 1) * 129 + r] = f.y * scale;
        lds[(c4 + 2) * 129 + r] = f.z * scale;
        lds[(c4 + 3) * 129 + r] = f.w * scale;
    }
    __syncthreads();

    // write phase: 64 out-rows (c), 128 bf16 each
    const int c = tid >> 2;                   // 0..63
    const int s = tid & 3;                    // 0..3
    #pragma unroll
    for (int j = 0; j < 4; ++j) {
        bf16x8 v;
        #pragma unroll
        for (int e = 0; e < 8; ++e)
            v[e] = f2bf(lds[c * 129 + s * 32 + j * 8 + e]);
        *(bf16x8*)&outp[outbase + (size_t)c * 1024 + s * 32 + j * 8] = v;
    }
}

// ---------------------------------------------------------------------------
// C = A[M][K] @ Bt[N][K]^T, A/Bt bf16 row-major, global_load_lds staging into
// double-buffered LDS, 1 barrier per K-step (DMA t+1 in flight across compute t).
// CMODE 0: C fp32 ldc.  CMODE 1: QKV split (QK bf16 / VT transposed).
// XCD-chunked block swizzle: flat ids remapped so XCD k owns a contiguous
// chunk (8 m-panels x all n-blocks) -> A slice L2-resident.  nwg % 8 == 0.
template<int CMODE, int BN>
__global__ __launch_bounds__(256) void gemm_bt(
    const unsigned short* __restrict__ A,
    const unsigned short* __restrict__ Bt,
    void* __restrict__ Cv,
    unsigned short* __restrict__ VT,
    int M, int N, int K, int ldc)
{
    __shared__ __align__(16) unsigned short As[2][128 * 32];
    __shared__ __align__(16) unsigned short Bs[2][BN * 32];

    // T1 swizzle (bijective: grid size divisible by 8)
    const int flat = blockIdx.y * gridDim.x + blockIdx.x;
    const int cpx  = (gridDim.x * gridDim.y) >> 3;
    const int swz  = (flat & 7) * cpx + (flat >> 3);
    const int m0 = (swz / gridDim.x) * 128;
    const int n0 = (swz % gridDim.x) * BN;

    const int tid  = threadIdx.x;
    const int w    = tid >> 6, lane = tid & 63;
    const int q4   = lane >> 4, lr  = lane & 15;
    constexpr int MI = (BN == 128) ? 4 : 2;
    const int rowBase = (BN == 128) ? (w >> 1) * 64 : w * 32;
    const int colBase = (BN == 128) ? (w & 1) * 64 : 0;

    const int ch   = tid & 3;
    const int row0 = tid >> 2;
    const int ldsOff = w * 512;   // halfwords; HW adds lane*16B

    const unsigned short* aP0 = &A [(size_t)(m0 + row0)      * K + ch * 8];
    const unsigned short* aP1 = &A [(size_t)(m0 + row0 + 64) * K + ch * 8];
    const unsigned short* bP0 = &Bt[(size_t)(n0 + row0)      * K + ch * 8];
    const unsigned short* bP1 = (BN == 128)
        ? &Bt[(size_t)(n0 + row0 + 64) * K + ch * 8] : nullptr;

    auto dma = [&](int buf, int k0) {
        gload_lds16(aP0 + k0, &As[buf][ldsOff]);
        gload_lds16(aP1 + k0, &As[buf][2048 + ldsOff]);
        gload_lds16(bP0 + k0, &Bs[buf][ldsOff]);
        if (BN == 128)
            gload_lds16(bP1 + k0, &Bs[buf][2048 + ldsOff]);
    };

    f32x4 acc[MI][4] = {};
    dma(0, 0);
    int cur = 0;

    for (int k0 = 0; k0 < K; k0 += 32) {
        __syncthreads();                          // drains DMA(k0) -> buf[cur] ready
        if (k0 + 32 < K) dma(cur ^ 1, k0 + 32);   // in flight during compute

        bf16x8 af[MI], bfv[4];
        #pragma unroll
        for (int i = 0; i < MI; ++i)
            af[i] = *(const bf16x8*)&As[cur][(rowBase + i * 16 + lr) * 32 + q4 * 8];
        #pragma unroll
        for (int j = 0; j < 4; ++j)
            bfv[j] = *(const bf16x8*)&Bs[cur][(colBase + j * 16 + lr) * 32 + q4 * 8];
        #pragma unroll
        for (int i = 0; i < MI; ++i)
            #pragma unroll
            for (int j = 0; j < 4; ++j)
                acc[i][j] = __builtin_amdgcn_mfma_f32_16x16x32_bf16(af[i], bfv[j], acc[i][j], 0, 0, 0);
        cur ^= 1;
    }

    #pragma unroll
    for (int i = 0; i < MI; ++i) {
        const int row = m0 + rowBase + i * 16 + q4 * 4;
        #pragma unroll
        for (int j = 0; j < 4; ++j) {
            const int col = n0 + colBase + j * 16 + lr;
            if (CMODE == 0) {
                float* C = (float*)Cv;
                #pragma unroll
                for (int p = 0; p < 4; ++p)
                    C[(size_t)(row + p) * ldc + col] = acc[i][j][p];
            } else {
                if (col < 2048) {
                    unsigned short* C = (unsigned short*)Cv;
                    #pragma unroll
                    for (int p = 0; p < 4; ++p)
                        C[(size_t)(row + p) * 2048 + col] = f2bf(acc[i][j][p]);
                } else {
                    const int c2 = col - 2048;
                    const int hh = c2 >> 6, dd = c2 & 63;
                    const int bb = row >> 11, ss = row & 2047;
                    ushortx4 v;
                    #pragma unroll
                    for (int p = 0; p < 4; ++p) v[p] = f2bf(acc[i][j][p]);
                    *(ushortx4*)&VT[((size_t)(bb * 16 + hh) * 64 + dd) * 2048 + ss] = v;
                }
            }
        }
    }
}

// ---------------------------------------------------------------------------
// Flash attention, transposed-P scheme.  QK[8192][2048] bf16 (Q|K),
// VT[(b*16+h)*64+d][2048] bf16.  WG = (bh, 128-q block); wave w: 32 q as
// 2 subtiles u.  64-key tiles, K/V in XOR-swizzled stride-64 double buffers
// filled by global_load_lds; S^T = K·Q^T; P^T moved to PV B-frags via
// permlane32_swap + permlane16_swap (pure VALU, no LDS); O^T = V^T·P^T.
// Softmax denominator accumulated by a ones-A-frag MFMA.  setprio(1) around
// MFMA clusters (T5).
__global__ __launch_bounds__(256, 4) void attn_flash(
    const unsigned short* __restrict__ QK,
    const unsigned short* __restrict__ VT,
    unsigned short* __restrict__ HC)        // [8192][1024] bf16
{
    const int bh  = blockIdx.x;   // b*16+h  (fastest dim -> XCD-pinned K/V reuse)
    const int qb  = blockIdx.y;   // 0..15
    const int b   = bh >> 4, h = bh & 15;
    const int tid = threadIdx.x;
    const int w   = tid >> 6, lane = tid & 63;
    const int q4  = lane >> 4, lr  = lane & 15;

    __shared__ __align__(16) unsigned short Ks [2][64 * 64];   // [key][dk] swizzled
    __shared__ __align__(16) unsigned short Vts[2][64 * 64];   // [d][key]  swizzled

    // DMA mapping: round R covers rows R*32+(tid>>3), chunk slot tid&7.
    const int drow   = tid >> 3;                       // 0..31
    const int gchunk = (tid & 7) ^ (drow & 7);         // global chunk for slot tid&7
    const unsigned short* Kg = QK + (size_t)(b * 2048) * 2048 + 1024 + h * 64;
    const unsigned short* Vg = VT + (size_t)bh * 64 * 2048;
    // running global pointers (advance per 64-key tile)
    const unsigned short* kP0 = Kg + (size_t)(drow)      * 2048 + gchunk * 8;
    const unsigned short* kP1 = Kg + (size_t)(drow + 32) * 2048 + gchunk * 8;
    const unsigned short* vP0 = Vg + (size_t)(drow)      * 2048 + gchunk * 8;
    const unsigned short* vP1 = Vg + (size_t)(drow + 32) * 2048 + gchunk * 8;
    const int ldsOff = w * 512;                        // halfwords; +lane*8 by HW

    auto dma = [&](int buf, int t) {
        gload_lds16(kP0 + (size_t)t * 131072, &Ks [buf][ldsOff]);
        gload_lds16(kP1 + (size_t)t * 131072, &Ks [buf][2048 + ldsOff]);
        gload_lds16(vP0 + t * 64,             &Vts[buf][ldsOff]);
        gload_lds16(vP1 + t * 64,             &Vts[buf][2048 + ldsOff]);
    };

    dma(0, 0);

    const int qrow0 = b * 2048 + qb * 128 + w * 32;
    bf16x8 qf[2][2];   // B-frag of Q^T == A-frag of Q: Q[q=lr][dk=c*32+q4*8+j]
    #pragma unroll
    for (int u = 0; u < 2; ++u)
        #pragma unroll
        for (int c = 0; c < 2; ++c)
            qf[u][c] = *(const bf16x8*)&QK[(size_t)(qrow0 + u * 16 + lr) * 2048
                                           + h * 64 + c * 32 + q4 * 8];

    const int lr7 = lr & 7;

    // ones A-fragment (bf16 1.0) for denominator row-sum MFMA
    const short oneb = (short)0x3F80;
    const bf16x8 onesf = { oneb, oneb, oneb, oneb, oneb, oneb, oneb, oneb };

    f32x4 o[2][4] = {};      // O^T[d=jd*16+q4*4+p][q=u*16+lr]
    f32x4 lsum[2] = {};      // denominator: all rows equal = sum_k P^T[k][q=lr]
    int cur = 0;

    for (int t = 0; t < 32; ++t) {
        __syncthreads();                       // drains DMA(t) -> buf[cur] ready
        if (t + 1 < 32) dma(cur ^ 1, t + 1);   // in flight during compute

        #pragma unroll
        for (int kc = 0; kc < 2; ++kc) {
            // --- S^T for this 32-key chunk (2 mt subtiles) ---
            unsigned int pk[2][2][2];          // packed P^T words [u][ml][i]
            #pragma unroll
            for (int ml = 0; ml < 2; ++ml) {
                const int mt = kc * 2 + ml;
                f32x4 st[2] = {};
                __builtin_amdgcn_s_setprio(1);
                #pragma unroll
                for (int c = 0; c < 2; ++c) {
                    const int slot = (c * 4 + q4) ^ lr7;
                    bf16x8 kf = *(const bf16x8*)&Ks[cur][(mt * 16 + lr) * 64 + slot * 8];
                    #pragma unroll
                    for (int u = 0; u < 2; ++u)
                        st[u] = __builtin_amdgcn_mfma_f32_16x16x32_bf16(kf, qf[u][c], st[u], 0, 0, 0);
                }
                __builtin_amdgcn_s_setprio(0);
                #pragma unroll
                for (int u = 0; u < 2; ++u) {
                    float e0 = __builtin_amdgcn_exp2f(st[u][0]);
                    float e1 = __builtin_amdgcn_exp2f(st[u][1]);
                    float e2 = __builtin_amdgcn_exp2f(st[u][2]);
                    float e3 = __builtin_amdgcn_exp2f(st[u][3]);
                    pk[u][ml][0] = pack_bf2(e1, e0);
                    pk[u][ml][1] = pack_bf2(e3, e2);
                }
            }

            // --- lane exchange P^T -> PV B-frags (pure VALU permlane) ---
            // dest lane d=(q4,lr): dword i needs keys q4*8+2i,2i+1 of this
            // 32-key chunk.  X=pk[ml=0][i] (keys 0-15), Y=pk[ml=1][i] (16-31):
            //   a = permlane32_swap(X,Y):  a0={X.lo,Y.lo}, a1={X.hi,Y.hi}
            //   b = permlane16_swap(a0,a1): b0[d]=wv[2i], b1[d]=wv[2i+1]
            bf16x8 pb[2];
            #pragma unroll
            for (int u = 0; u < 2; ++u) {
                uint2v a0 = __builtin_amdgcn_permlane32_swap(pk[u][0][0], pk[u][1][0], false, false);
                uint2v b0 = __builtin_amdgcn_permlane16_swap(a0[0], a0[1], false, false);
                uint2v a1 = __builtin_amdgcn_permlane32_swap(pk[u][0][1], pk[u][1][1], false, false);
                uint2v b1 = __builtin_amdgcn_permlane16_swap(a1[0], a1[1], false, false);
                int4 wv;
                wv.x = (int)b0[0];
                wv.y = (int)b1[0];
                wv.z = (int)b0[1];
                wv.w = (int)b1[1];
                pb[u] = *(bf16x8*)&wv;
            }

            // --- PV: O^T += V^T · P^T  (+ denominator row-sum) ---
            __builtin_amdgcn_s_setprio(1);
            #pragma unroll
            for (int u = 0; u < 2; ++u)
                lsum[u] = __builtin_amdgcn_mfma_f32_16x16x32_bf16(onesf, pb[u], lsum[u], 0, 0, 0);
            #pragma unroll
            for (int jd = 0; jd < 4; ++jd) {
                const int slot = (kc * 4 + q4) ^ lr7;
                bf16x8 vf = *(const bf16x8*)&Vts[cur][(jd * 16 + lr) * 64 + slot * 8];
                #pragma unroll
                for (int u = 0; u < 2; ++u)
                    o[u][jd] = __builtin_amdgcn_mfma_f32_16x16x32_bf16(vf, pb[u], o[u][jd], 0, 0, 0);
            }
            __builtin_amdgcn_s_setprio(0);
        }
        cur ^= 1;
    }

    #pragma unroll
    for (int u = 0; u < 2; ++u) {
        const float inv = __builtin_amdgcn_rcpf(lsum[u][0]);
        const size_t rowO = (size_t)(qrow0 + u * 16 + lr);
        #pragma unroll
        for (int jd = 0; jd < 4; ++jd) {
            ushortx4 v;
            #pragma unroll
            for (int p = 0; p < 4; ++p)
                v[p] = f2bf(o[u][jd][p] * inv);
            *(ushortx4*)&HC[rowO * 1024 + h * 64 + jd * 16 + q4 * 4] = v;
        }
    }
}

// ---------------------------------------------------------------------------
extern "C" void kernel_launch(void* const* d_in, const int* in_sizes, int n_in,
                              void* d_out, int out_size, void* d_ws, size_t ws_size,
                              hipStream_t stream)
{
    const float* x  = (const float*)d_in[0];
    const float* Wq = (const float*)d_in[1];
    const float* Wk = (const float*)d_in[2];
    const float* Wv = (const float*)d_in[3];
    const float* Wo = (const float*)d_in[4];
    float* out = (float*)d_out;

    char* ws = (char*)d_ws;
    unsigned short* XB    = (unsigned short*)(ws);              // 16777216 (aliases HC)
    unsigned short* HC    = (unsigned short*)(ws);
    unsigned short* WQKVT = (unsigned short*)(ws + 16777216);   // 6291456
    unsigned short* WOT   = (unsigned short*)(ws + 23068672);   // 2097152
    unsigned short* QK    = (unsigned short*)(ws + 25165824);   // 33554432
    unsigned short* VT    = (unsigned short*)(ws + 58720256);   // 16777216
    // total ws: 75497472 B (~72 MiB)

    pack_all<<<4608, 256, 0, stream>>>(x, Wq, Wk, Wv, Wo, XB, WQKVT, WOT);
    gemm_bt<1, 128><<<dim3(24, 64), 256, 0, stream>>>(XB, WQKVT, QK, VT, 8192, 3072, 1024, 0);
    attn_flash<<<dim3(64, 16), 256, 0, stream>>>(QK, VT, HC);
    gemm_bt<0, 128><<<dim3(8, 64), 256, 0, stream>>>(HC, WOT, out, nullptr, 8192, 1024, 1024, 1024);
}